// Round 14
// baseline (468.797 us; speedup 1.0000x reference)
//
#include <hip/hip_runtime.h>
#include <math.h>

static constexpr int L_ = 2, H_ = 12, D_ = 768, DH_ = 3072, V_ = 32000,
                     S_ = 1024, B_ = 2;
static constexpr int M_ = B_ * S_;  // 2048 token rows

typedef __attribute__((ext_vector_type(4))) float f32x4;
typedef __attribute__((ext_vector_type(8))) short s16x8;   // 8 bf16 = 4 VGPR
typedef __attribute__((ext_vector_type(2))) unsigned int u32x2;
typedef __attribute__((ext_vector_type(4))) unsigned int u32x4;

__device__ __forceinline__ unsigned short f2bf(float f) {
    unsigned u = __builtin_bit_cast(unsigned, f);
    u = (u + 0x7FFFu + ((u >> 16) & 1u)) >> 16;   // RTNE
    return (unsigned short)u;
}
__device__ __forceinline__ unsigned pack2(float a, float b) {
    return (unsigned)f2bf(a) | ((unsigned)f2bf(b) << 16);
}

__device__ __forceinline__ void gld16(const void* g, void* l) {
    __builtin_amdgcn_global_load_lds(
        (const __attribute__((address_space(1))) unsigned int*)g,
        (__attribute__((address_space(3))) unsigned int*)l, 16, 0, 0);
}

// ---------------------------------------------------------------------------
// Weight transpose: in [K][N] fp32 (mat z at z*K*N) -> out [N][K] bf16.
// ---------------------------------------------------------------------------
__global__ __launch_bounds__(256) void wtr_kernel(
    const float* __restrict__ in, unsigned short* __restrict__ out, int K, int N)
{
    __shared__ unsigned short t[64 * 68];
    const size_t mo = (size_t)blockIdx.z * K * N;
    in  += mo; out += mo;
    const int n0 = blockIdx.x * 64, k0 = blockIdx.y * 64;
    const int tid = threadIdx.x;
    const int kr = tid >> 2, nc = (tid & 3) * 16;
    const float* src = in + (size_t)(k0 + kr) * N + n0 + nc;
    #pragma unroll
    for (int j = 0; j < 4; ++j) {
        const float4 v = *(const float4*)(src + j * 4);
        *(u32x2*)&t[kr * 68 + nc + j * 4] = (u32x2){pack2(v.x, v.y), pack2(v.z, v.w)};
    }
    __syncthreads();
    const int nr = tid >> 2, kc = (tid & 3) * 16;
    unsigned short v16[16];
    #pragma unroll
    for (int j = 0; j < 16; ++j) v16[j] = t[(kc + j) * 68 + nr];
    unsigned short* dst = out + (size_t)(n0 + nr) * K + k0 + kc;
    ((u32x4*)dst)[0] = *(u32x4*)&v16[0];
    ((u32x4*)dst)[1] = *(u32x4*)&v16[8];
}

// Merged QKV transpose: 3 matrices x L_*H_ head-slices, one launch.
__global__ __launch_bounds__(256) void wtr3_kernel(
    const float* __restrict__ Wq, const float* __restrict__ Wk,
    const float* __restrict__ Wv, unsigned short* __restrict__ oq,
    unsigned short* __restrict__ ok, unsigned short* __restrict__ ov)
{
    __shared__ unsigned short t[64 * 68];
    const int z = blockIdx.z;
    const int which = z / 24, zz = z - which * 24;
    const float* in = (which == 0) ? Wq : (which == 1) ? Wk : Wv;
    unsigned short* out = (which == 0) ? oq : (which == 1) ? ok : ov;
    const size_t mo = (size_t)zz * D_ * 64;
    in += mo; out += mo;
    const int k0 = blockIdx.y * 64;
    const int tid = threadIdx.x;
    const int kr = tid >> 2, nc = (tid & 3) * 16;
    const float* src = in + (size_t)(k0 + kr) * 64 + nc;
    #pragma unroll
    for (int j = 0; j < 4; ++j) {
        const float4 v = *(const float4*)(src + j * 4);
        *(u32x2*)&t[kr * 68 + nc + j * 4] = (u32x2){pack2(v.x, v.y), pack2(v.z, v.w)};
    }
    __syncthreads();
    const int nr = tid >> 2, kc = (tid & 3) * 16;
    unsigned short v16[16];
    #pragma unroll
    for (int j = 0; j < 16; ++j) v16[j] = t[(kc + j) * 68 + nr];
    unsigned short* dst = out + (size_t)nr * D_ + k0 + kc;
    ((u32x4*)dst)[0] = *(u32x4*)&v16[0];
    ((u32x4*)dst)[1] = *(u32x4*)&v16[8];
}

__device__ __forceinline__ void xcd_decode(int& bx, int& by) {
    const int gx = gridDim.x, gy = gridDim.y;
    const int nwg = gx * gy;
    const int flat = blockIdx.y * gx + blockIdx.x;
    const int s = (flat & 7) * (nwg >> 3) + (flat >> 3);
    bx = s / gy;
    by = s % gy;
}

// ---------------------------------------------------------------------------
// 64x128 tile GEMM — workhorse for mid-size GEMMs. 256 threads = 4 waves 1x4;
// per-wave 64x32, acc 4x2. LDS 24 KiB -> 5+ blocks/CU. Granule-XOR layout.
// act 0: f32+bias. 1: f32+bias+gelu. 2: bf16+bias [M][N].
// 3: V^T bf16+bias [B][H][64][S] (LDS-bounced coalesced). 4: f32 raw (splitK).
// ---------------------------------------------------------------------------
__device__ __forceinline__ void bt64_body(
    const unsigned short* __restrict__ A, const unsigned short* __restrict__ BT,
    const float* __restrict__ bias, void* __restrict__ Cp,
    int N, int K, int act, int k0off, int klen, int bx, int by)
{
    __shared__ unsigned short AB[12288];   // As = AB (8KB), Bs = AB+4096 (16KB)
    unsigned short* As = AB;
    unsigned short* Bs = AB + 4096;
    const int tid = threadIdx.x;
    const int l = tid & 63, w = tid >> 6;
    const int lq = l & 15, lg = l >> 4;
    const int brow = by * 64, bn = bx * 128;

    f32x4 acc[4][2];
    #pragma unroll
    for (int i = 0; i < 4; ++i)
        #pragma unroll
        for (int j = 0; j < 2; ++j) acc[i][j] = (f32x4)0.f;

    const int arow = tid >> 3;                    // 0..31
    const int aq   = (tid & 7) ^ (arow & 7);
    const unsigned short* Abase = A  + (size_t)(brow + arow) * K + k0off + aq * 8;
    const unsigned short* Bbase = BT + (size_t)(bn   + arow) * K + k0off + aq * 8;

    for (int k0 = 0; k0 < klen; k0 += 64) {
        #pragma unroll
        for (int r = 0; r < 2; ++r)
            gld16(Abase + (size_t)r * 32 * K + k0, (char*)As + r * 4096 + tid * 16);
        #pragma unroll
        for (int r = 0; r < 4; ++r)
            gld16(Bbase + (size_t)r * 32 * K + k0, (char*)Bs + r * 4096 + tid * 16);
        __syncthreads();

        #pragma unroll
        for (int kk = 0; kk < 2; ++kk) {
            s16x8 af[4], bf[2];
            #pragma unroll
            for (int mf = 0; mf < 4; ++mf) {
                const int row = mf * 16 + lq;
                const int gg  = (kk * 4 + lg) ^ (row & 7);
                af[mf] = *(const s16x8*)((const char*)As + row * 128 + gg * 16);
            }
            #pragma unroll
            for (int nf = 0; nf < 2; ++nf) {
                const int col = w * 32 + nf * 16 + lq;
                const int gg  = (kk * 4 + lg) ^ (col & 7);
                bf[nf] = *(const s16x8*)((const char*)Bs + col * 128 + gg * 16);
            }
            #pragma unroll
            for (int mf = 0; mf < 4; ++mf)
                #pragma unroll
                for (int nf = 0; nf < 2; ++nf)
                    acc[mf][nf] = __builtin_amdgcn_mfma_f32_16x16x32_bf16(
                        af[mf], bf[nf], acc[mf][nf], 0, 0, 0);
        }
        __syncthreads();
    }

    if (act == 3) {
        #pragma unroll
        for (int nf = 0; nf < 2; ++nf) {
            const int c = w * 32 + nf * 16 + lq;
            const float bb = bias[bn + c];
            #pragma unroll
            for (int mf = 0; mf < 4; ++mf) {
                const int srel = mf * 16 + lg * 4;
                u32x2 pk;
                pk[0] = pack2(acc[mf][nf][0] + bb, acc[mf][nf][1] + bb);
                pk[1] = pack2(acc[mf][nf][2] + bb, acc[mf][nf][3] + bb);
                const int byo = (c * 128 + srel * 2) ^ ((c & 7) << 4);
                *(u32x2*)((char*)AB + byo) = pk;
            }
        }
        __syncthreads();
        const int row = tid >> 1, half = tid & 1;
        const int gcf = bn + row;
        const int head = gcf >> 6, d = gcf & 63;
        const int b = brow >> 10;
        const int sb = (brow & (S_ - 1)) + half * 32;
        unsigned short* dst = (unsigned short*)Cp +
            (((size_t)b * H_ + head) * 64 + d) * S_ + sb;
        #pragma unroll
        for (int u = 0; u < 4; ++u) {
            const int byo = (row * 128 + half * 64 + u * 16) ^ ((row & 7) << 4);
            ((u32x4*)dst)[u] = *(const u32x4*)((const char*)AB + byo);
        }
        return;
    }
    #pragma unroll
    for (int nf = 0; nf < 2; ++nf) {
        const int gcol = bn + w * 32 + nf * 16 + lq;
        const float bb = (act == 4) ? 0.f : bias[gcol];
        #pragma unroll
        for (int mf = 0; mf < 4; ++mf)
            #pragma unroll
            for (int rg = 0; rg < 4; ++rg) {
                const int grow = brow + mf * 16 + lg * 4 + rg;
                float vv = acc[mf][nf][rg] + bb;
                if (act == 1) vv = 0.5f * vv * (1.0f + erff(vv * 0.70710678118654752f));
                if (act == 2)
                    ((unsigned short*)Cp)[(size_t)grow * N + gcol] = f2bf(vv);
                else
                    ((float*)Cp)[(size_t)grow * N + gcol] = vv;
            }
    }
}

__global__ __launch_bounds__(256) void gemm_bt64(
    const unsigned short* __restrict__ A, const unsigned short* __restrict__ BT,
    const float* __restrict__ bias, void* __restrict__ C, int N, int K, int act)
{
    int bx, by; xcd_decode(bx, by);
    bt64_body(A, BT, bias, C, N, K, act, 0, K, bx, by);
}

// ---------------------------------------------------------------------------
// 64x64 tile GEMM for Q/K projections: grid (12, 32, 2) = 768 blocks (3/CU).
// 16 KiB LDS. bf16 out [M][768].
// ---------------------------------------------------------------------------
__global__ __launch_bounds__(256) void gemm_qk64n(
    const unsigned short* __restrict__ A,
    const unsigned short* __restrict__ qT, const unsigned short* __restrict__ kT,
    const float* __restrict__ bq, const float* __restrict__ bk,
    unsigned short* __restrict__ q, unsigned short* __restrict__ k)
{
    __shared__ unsigned short As[4096];    // [64 rows][64 k]
    __shared__ unsigned short Bs[4096];    // [64 cols][64 k]
    const unsigned short* BT = (blockIdx.z == 0) ? qT : kT;
    const float* bias = (blockIdx.z == 0) ? bq : bk;
    unsigned short* C = (blockIdx.z == 0) ? q : k;
    const int tid = threadIdx.x;
    const int l = tid & 63, w = tid >> 6;
    const int lq = l & 15, lg = l >> 4;
    int bx, by; xcd_decode(bx, by);
    const int brow = by * 64, bn = bx * 64;
    const int K = 768;

    f32x4 acc[4];
    #pragma unroll
    for (int i = 0; i < 4; ++i) acc[i] = (f32x4)0.f;

    const int arow = tid >> 3;                    // 0..31
    const int aq   = (tid & 7) ^ (arow & 7);
    const unsigned short* Abase = A  + (size_t)(brow + arow) * K + aq * 8;
    const unsigned short* Bbase = BT + (size_t)(bn   + arow) * K + aq * 8;

    for (int k0 = 0; k0 < K; k0 += 64) {
        #pragma unroll
        for (int r = 0; r < 2; ++r) {
            gld16(Abase + (size_t)r * 32 * K + k0, (char*)As + r * 4096 + tid * 16);
            gld16(Bbase + (size_t)r * 32 * K + k0, (char*)Bs + r * 4096 + tid * 16);
        }
        __syncthreads();

        #pragma unroll
        for (int kk = 0; kk < 2; ++kk) {
            s16x8 af[4], bf;
            #pragma unroll
            for (int mf = 0; mf < 4; ++mf) {
                const int row = mf * 16 + lq;
                const int gg  = (kk * 4 + lg) ^ (row & 7);
                af[mf] = *(const s16x8*)((const char*)As + row * 128 + gg * 16);
            }
            {
                const int col = w * 16 + lq;
                const int gg  = (kk * 4 + lg) ^ (col & 7);
                bf = *(const s16x8*)((const char*)Bs + col * 128 + gg * 16);
            }
            #pragma unroll
            for (int mf = 0; mf < 4; ++mf)
                acc[mf] = __builtin_amdgcn_mfma_f32_16x16x32_bf16(
                    af[mf], bf, acc[mf], 0, 0, 0);
        }
        __syncthreads();
    }

    const int gcol = bn + w * 16 + lq;
    const float bb = bias[gcol];
    #pragma unroll
    for (int mf = 0; mf < 4; ++mf)
        #pragma unroll
        for (int rg = 0; rg < 4; ++rg) {
            const int grow = brow + mf * 16 + lg * 4 + rg;
            C[(size_t)grow * 768 + gcol] = f2bf(acc[mf][rg] + bb);
        }
}

// V projection (act3 V^T): grid (6, 32).
__global__ __launch_bounds__(256) void gemm_v64(
    const unsigned short* __restrict__ A, const unsigned short* __restrict__ vT,
    const float* __restrict__ bv, unsigned short* __restrict__ v)
{
    int bx, by; xcd_decode(bx, by);
    bt64_body(A, vT, bv, v, 768, 768, 3, 0, 768, bx, by);
}

// W2 split-K: grid (6, 32, 2). z=0 -> partial0 (with bias), z=1 -> partial1 raw.
__global__ __launch_bounds__(256) void gemm_w2sk(
    const unsigned short* __restrict__ A, const unsigned short* __restrict__ BT,
    const float* __restrict__ bias, float* __restrict__ C0, float* __restrict__ C1)
{
    int bx, by; xcd_decode(bx, by);
    if (blockIdx.z == 0)
        bt64_body(A, BT, bias, C0, 768, DH_, 0, 0, 1536, bx, by);
    else
        bt64_body(A, BT, bias, C1, 768, DH_, 4, 1536, 1536, bx, by);
}

// Wo split-K: grid (6, 32, 2). K=768 halves.
__global__ __launch_bounds__(256) void gemm_wosk(
    const unsigned short* __restrict__ A, const unsigned short* __restrict__ BT,
    const float* __restrict__ bias, float* __restrict__ C0, float* __restrict__ C1)
{
    int bx, by; xcd_decode(bx, by);
    if (blockIdx.z == 0)
        bt64_body(A, BT, bias, C0, 768, 768, 0, 0, 384, bx, by);
    else
        bt64_body(A, BT, bias, C1, 768, 768, 4, 384, 384, bx, by);
}

// ---------------------------------------------------------------------------
// 256x256 8-wave GEMM for the logits matmul (round-8 schedule, best variant).
// ---------------------------------------------------------------------------
__global__ __launch_bounds__(512, 2) void gemm_deep(
    const unsigned short* __restrict__ A, const unsigned short* __restrict__ BT,
    const float* __restrict__ bias, float* __restrict__ C, int N, int K)
{
    __shared__ char lds[131072];   // A: c*32768; B: 65536 + c*32768
    const int tid = threadIdx.x;
    const int l = tid & 63, w = tid >> 6;
    const int wr = w >> 2, wc = w & 3;
    const int lq = l & 15, lg = l >> 4;

    int bx, by;
    {
        const int gx = gridDim.x, gy = gridDim.y;
        const int nwg = gx * gy;
        const int flat = blockIdx.y * gx + blockIdx.x;
        const int s = (flat & 7) * (nwg >> 3) + (flat >> 3);
        bx = s / gy; by = s % gy;
    }
    const int brow = by * 256, bn = bx * 256;
    const int NT = K >> 6;   // 12

    const int srow = (w << 3) + (l >> 3);        // 0..63
    const int sgr  = (l & 7) ^ (l >> 3);
    const size_t soff = (size_t)srow * K + sgr * 8;
    const unsigned short* Ag = A  + (size_t)brow * K + soff;
    const unsigned short* Bg = BT + (size_t)bn   * K + soff;
    const size_t r64  = (size_t)64 * K;
    const size_t r128 = (size_t)128 * K;
    char* const dA = lds + w * 1024;
    char* const dB = lds + 65536 + w * 1024;

#define STG_A(CB, HF, KT) do {                                                   \
    gld16(Ag + (size_t)(HF) * r128 + (size_t)(KT) * 64,                          \
          dA + (CB) * 32768 + (HF) * 16384);                                     \
    gld16(Ag + (size_t)(HF) * r128 + r64 + (size_t)(KT) * 64,                    \
          dA + (CB) * 32768 + (HF) * 16384 + 8192); } while (0)
#define STG_B(CB, HF, KT) do {                                                   \
    gld16(Bg + (size_t)(HF) * r128 + (size_t)(KT) * 64,                          \
          dB + (CB) * 32768 + (HF) * 16384);                                     \
    gld16(Bg + (size_t)(HF) * r128 + r64 + (size_t)(KT) * 64,                    \
          dB + (CB) * 32768 + (HF) * 16384 + 8192); } while (0)

    f32x4 acc[8][4];
    #pragma unroll
    for (int i = 0; i < 8; ++i)
        #pragma unroll
        for (int j = 0; j < 4; ++j) acc[i][j] = (f32x4)0.f;

    STG_A(0, 0, 0); STG_A(0, 1, 0); STG_B(0, 0, 0); STG_B(0, 1, 0);
    STG_A(1, 0, 1); STG_B(1, 0, 1);
    asm volatile("s_waitcnt vmcnt(4)" ::: "memory");
    __builtin_amdgcn_s_barrier();

    for (int t = 0; t < NT; ++t) {
        const int c = t & 1;
        const char* Ab = lds + c * 32768;
        const char* Bb = lds + 65536 + c * 32768;
        s16x8 af[4], bf[4];

        #pragma unroll
        for (int mf = 0; mf < 4; ++mf) {
            const int row = wr * 128 + mf * 16 + lq;
            af[mf] = *(const s16x8*)(Ab + row * 128 + ((lg ^ (row & 7)) << 4));
        }
        #pragma unroll
        for (int nf = 0; nf < 4; ++nf) {
            const int col = wc * 64 + nf * 16 + lq;
            bf[nf] = *(const s16x8*)(Bb + col * 128 + ((lg ^ (col & 7)) << 4));
        }
        if (t + 1 < NT) STG_A(c ^ 1, 1, t + 1);
        asm volatile("s_waitcnt lgkmcnt(0)" ::: "memory");
        __builtin_amdgcn_sched_barrier(0);
        __builtin_amdgcn_s_barrier();
        __builtin_amdgcn_s_setprio(1);
        #pragma unroll
        for (int mf = 0; mf < 4; ++mf)
            #pragma unroll
            for (int nf = 0; nf < 4; ++nf)
                acc[mf][nf] = __builtin_amdgcn_mfma_f32_16x16x32_bf16(
                    af[mf], bf[nf], acc[mf][nf], 0, 0, 0);
        __builtin_amdgcn_s_setprio(0);
        __builtin_amdgcn_s_barrier();

        #pragma unroll
        for (int mf = 0; mf < 4; ++mf) {
            const int row = wr * 128 + (mf + 4) * 16 + lq;
            af[mf] = *(const s16x8*)(Ab + row * 128 + ((lg ^ (row & 7)) << 4));
        }
        if (t + 1 < NT) STG_B(c ^ 1, 1, t + 1);
        asm volatile("s_waitcnt lgkmcnt(0)" ::: "memory");
        __builtin_amdgcn_sched_barrier(0);
        __builtin_amdgcn_s_barrier();
        __builtin_amdgcn_s_setprio(1);
        #pragma unroll
        for (int mf = 0; mf < 4; ++mf)
            #pragma unroll
            for (int nf = 0; nf < 4; ++nf)
                acc[mf + 4][nf] = __builtin_amdgcn_mfma_f32_16x16x32_bf16(
                    af[mf], bf[nf], acc[mf + 4][nf], 0, 0, 0);
        __builtin_amdgcn_s_setprio(0);
        __builtin_amdgcn_s_barrier();

        #pragma unroll
        for (int mf = 0; mf < 4; ++mf) {
            const int row = wr * 128 + mf * 16 + lq;
            af[mf] = *(const s16x8*)(Ab + row * 128 + (((4 + lg) ^ (row & 7)) << 4));
        }
        #pragma unroll
        for (int nf = 0; nf < 4; ++nf) {
            const int col = wc * 64 + nf * 16 + lq;
            bf[nf] = *(const s16x8*)(Bb + col * 128 + (((4 + lg) ^ (col & 7)) << 4));
        }
        asm volatile("s_waitcnt lgkmcnt(0)" ::: "memory");
        __builtin_amdgcn_sched_barrier(0);
        __builtin_amdgcn_s_barrier();
        __builtin_amdgcn_s_setprio(1);
        #pragma unroll
        for (int mf = 0; mf < 4; ++mf)
            #pragma unroll
            for (int nf = 0; nf < 4; ++nf)
                acc[mf][nf] = __builtin_amdgcn_mfma_f32_16x16x32_bf16(
                    af[mf], bf[nf], acc[mf][nf], 0, 0, 0);
        __builtin_amdgcn_s_setprio(0);
        __builtin_amdgcn_s_barrier();

        #pragma unroll
        for (int mf = 0; mf < 4; ++mf) {
            const int row = wr * 128 + (mf + 4) * 16 + lq;
            af[mf] = *(const s16x8*)(Ab + row * 128 + (((4 + lg) ^ (row & 7)) << 4));
        }
        asm volatile("s_waitcnt lgkmcnt(0)" ::: "memory");
        __builtin_amdgcn_sched_barrier(0);
        __builtin_amdgcn_s_barrier();
        __builtin_amdgcn_s_setprio(1);
        #pragma unroll
        for (int mf = 0; mf < 4; ++mf)
            #pragma unroll
            for (int nf = 0; nf < 4; ++nf)
                acc[mf + 4][nf] = __builtin_amdgcn_mfma_f32_16x16x32_bf16(
                    af[mf], bf[nf], acc[mf + 4][nf], 0, 0, 0);
        __builtin_amdgcn_s_setprio(0);

        if (t + 2 < NT) {
            STG_A(c, 0, t + 2); STG_B(c, 0, t + 2);
            asm volatile("s_waitcnt vmcnt(4)" ::: "memory");
            __builtin_amdgcn_s_barrier();
        } else if (t + 1 < NT) {
            asm volatile("s_waitcnt vmcnt(0)" ::: "memory");
            __builtin_amdgcn_s_barrier();
        }
    }
#undef STG_A
#undef STG_B

    #pragma unroll
    for (int nf = 0; nf < 4; ++nf) {
        const int gcol = bn + wc * 64 + nf * 16 + lq;
        const float bb = bias[gcol];
        #pragma unroll
        for (int mf = 0; mf < 8; ++mf)
            #pragma unroll
            for (int rg = 0; rg < 4; ++rg) {
                const int grow = brow + wr * 128 + mf * 16 + lg * 4 + rg;
                C[(size_t)grow * N + gcol] = acc[mf][nf][rg] + bb;
            }
    }
}

// ---------------------------------------------------------------------------
// Fallback GEMM (fp32 B in [K][N]) — only if ws can't hold transposed Wout.
// ---------------------------------------------------------------------------
__global__ __launch_bounds__(256) void gemm_f32b(
    const unsigned short* __restrict__ A, const float* __restrict__ B,
    const float* __restrict__ bias, float* __restrict__ C, int N, int K)
{
    __shared__ unsigned short As[8192];
    __shared__ unsigned short Bs[8192];
    const int tid = threadIdx.x;
    const int l   = tid & 63, wid = tid >> 6;
    const int wr  = wid >> 1, wc = wid & 1;
    const int brow = blockIdx.y * 128, bn = blockIdx.x * 128;
    f32x4 acc[4][4];
    #pragma unroll
    for (int i = 0; i < 4; ++i)
        #pragma unroll
        for (int j = 0; j < 4; ++j) acc[i][j] = (f32x4)0.f;
    const int arow = tid >> 3;
    const int aq   = (tid & 7) ^ (arow & 7);
    const int bkq  = tid >> 5, bnq = tid & 31;
    for (int k0 = 0; k0 < K; k0 += 64) {
        #pragma unroll
        for (int r = 0; r < 4; ++r)
            gld16(A + (size_t)(brow + r * 32 + arow) * K + k0 + aq * 8,
                  (char*)As + r * 4096 + wid * 1024);
        #pragma unroll
        for (int r = 0; r < 2; ++r) {
            const int kb = r * 32 + bkq * 4;
            const float* pp = B + (size_t)(k0 + kb) * N + bn + bnq * 4;
            const float4 v0 = *(const float4*)(pp);
            const float4 v1 = *(const float4*)(pp + N);
            const float4 v2 = *(const float4*)(pp + 2 * (size_t)N);
            const float4 v3 = *(const float4*)(pp + 3 * (size_t)N);
            const int g = kb >> 3, bytek = (kb & 4) * 2;
            const float* f0 = (const float*)&v0; const float* f1 = (const float*)&v1;
            const float* f2 = (const float*)&v2; const float* f3 = (const float*)&v3;
            #pragma unroll
            for (int i = 0; i < 4; ++i) {
                const int n = bnq * 4 + i;
                char* dst = (char*)Bs + n * 128 + ((g ^ (n & 7)) * 16) + bytek;
                *(u32x2*)dst = (u32x2){pack2(f0[i], f1[i]), pack2(f2[i], f3[i])};
            }
        }
        __syncthreads();
        #pragma unroll
        for (int kk = 0; kk < 2; ++kk) {
            s16x8 af[4], bf[4];
            #pragma unroll
            for (int mf = 0; mf < 4; ++mf) {
                const int row = wr * 64 + mf * 16 + (l & 15);
                const int gg  = (kk * 4 + (l >> 4)) ^ (row & 7);
                af[mf] = *(const s16x8*)((const char*)As + row * 128 + gg * 16);
            }
            #pragma unroll
            for (int nf = 0; nf < 4; ++nf) {
                const int col = wc * 64 + nf * 16 + (l & 15);
                const int gg  = (kk * 4 + (l >> 4)) ^ (col & 7);
                bf[nf] = *(const s16x8*)((const char*)Bs + col * 128 + gg * 16);
            }
            #pragma unroll
            for (int mf = 0; mf < 4; ++mf)
                #pragma unroll
                for (int nf = 0; nf < 4; ++nf)
                    acc[mf][nf] = __builtin_amdgcn_mfma_f32_16x16x32_bf16(
                        af[mf], bf[nf], acc[mf][nf], 0, 0, 0);
        }
        __syncthreads();
    }
    const int lr = l >> 4, lc = l & 15;
    #pragma unroll
    for (int nf = 0; nf < 4; ++nf) {
        const int gcol = bn + wc * 64 + nf * 16 + lc;
        const float bb = bias[gcol];
        #pragma unroll
        for (int mf = 0; mf < 4; ++mf)
            #pragma unroll
            for (int rg = 0; rg < 4; ++rg) {
                const int grow = brow + wr * 64 + mf * 16 + lr * 4 + rg;
                C[(size_t)grow * N + gcol] = acc[mf][nf][rg] + bb;
            }
    }
}

// ---------------------------------------------------------------------------
// Flash attention v3: mask addend + setprio + dbuf + balance remap.
// ---------------------------------------------------------------------------
__global__ __launch_bounds__(256) void fattn_kernel(
    const unsigned short* __restrict__ qm, const unsigned short* __restrict__ km,
    const unsigned short* __restrict__ vt, const int* __restrict__ ign,
    unsigned short* __restrict__ sab)
{
    __shared__ unsigned short Ks[2][4096];
    __shared__ unsigned short VTs[2][4096];
    __shared__ float addvs[2][64];
    __shared__ unsigned short PTs[4][1024];

    const int hh = blockIdx.y, b = blockIdx.z;
    const int zy = b * 12 + hh;
    const int qt = (zy >= 16) ? (15 - blockIdx.x) : blockIdx.x;

    const int tid = threadIdx.x;
    const int l = tid & 63, w = tid >> 6;
    const int g = l >> 4, lq = l & 15;
    const int i = qt * 64 + w * 16 + lq;

    const size_t qgb = ((size_t)(b * S_ + i)) * D_ + hh * 64;
    const s16x8 qf0 = *(const s16x8*)(qm + qgb + g * 8);
    const s16x8 qf1 = *(const s16x8*)(qm + qgb + 32 + g * 8);

    f32x4 accO[4];
    #pragma unroll
    for (int d = 0; d < 4; ++d) accO[d] = (f32x4)0.f;
    float mrun = -1e30f, lrun = 0.f;

    const int srow = tid >> 3, sg = tid & 7;
    const size_t kbase = (size_t)(b * S_) * D_ + hh * 64;
    const size_t vbase = ((size_t)(b * H_ + hh) * 64) * S_;

    auto stage = [&](int t, int bufi) {
        const int j0 = t * 64;
        #pragma unroll
        for (int r = 0; r < 2; ++r) {
            const int row = r * 32 + srow;
            const int gsw = (sg ^ (row & 7)) * 8;
            gld16(km + kbase + (size_t)(j0 + row) * D_ + gsw,
                  (char*)&Ks[bufi][0] + (r * 256 + tid) * 16);
            gld16(vt + vbase + (size_t)row * S_ + j0 + gsw,
                  (char*)&VTs[bufi][0] + (r * 256 + tid) * 16);
        }
        if (tid < 64)
            addvs[bufi][tid] = (ign[b * S_ + j0 + tid] == 0) ? 0.f : -INFINITY;
    };

    stage(0, 0);
    asm volatile("s_waitcnt vmcnt(0) lgkmcnt(0)" ::: "memory");
    __syncthreads();

    for (int t = 0; t <= qt; ++t) {
        const int cur = t & 1;
        const int j0 = t * 64;
        if (t < qt) stage(t + 1, cur ^ 1);

        f32x4 adv[4];
        #pragma unroll
        for (int kf = 0; kf < 4; ++kf)
            adv[kf] = *(const f32x4*)&addvs[cur][kf * 16 + g * 4];

        f32x4 sacc[4];
        #pragma unroll
        for (int kf = 0; kf < 4; ++kf) sacc[kf] = (f32x4)0.f;
        __builtin_amdgcn_s_setprio(1);
        #pragma unroll
        for (int kk = 0; kk < 2; ++kk) {
            const s16x8 qv = kk ? qf1 : qf0;
            #pragma unroll
            for (int kf = 0; kf < 4; ++kf) {
                const int row = kf * 16 + lq;
                const s16x8 kv = *(const s16x8*)((const char*)&Ks[cur][0] + row * 128 +
                                                 (((kk * 4 + g) ^ (row & 7)) * 16));
                sacc[kf] = __builtin_amdgcn_mfma_f32_16x16x32_bf16(kv, qv, sacc[kf], 0, 0, 0);
            }
        }
        __builtin_amdgcn_s_setprio(0);

        float tmax = -INFINITY;
        if (t < qt) {
            #pragma unroll
            for (int kf = 0; kf < 4; ++kf)
                #pragma unroll
                for (int rg = 0; rg < 4; ++rg) {
                    const float s = fmaf(sacc[kf][rg], 0.125f, adv[kf][rg]);
                    sacc[kf][rg] = s;
                    tmax = fmaxf(tmax, s);
                }
        } else {
            #pragma unroll
            for (int kf = 0; kf < 4; ++kf)
                #pragma unroll
                for (int rg = 0; rg < 4; ++rg) {
                    const int j = j0 + kf * 16 + g * 4 + rg;
                    const float sv = sacc[kf][rg] * 0.125f;
                    const float s = (j > i) ? -INFINITY
                                  : (j == i ? sv : sv + adv[kf][rg]);
                    sacc[kf][rg] = s;
                    tmax = fmaxf(tmax, s);
                }
        }
        tmax = fmaxf(tmax, __shfl_xor(tmax, 16));
        tmax = fmaxf(tmax, __shfl_xor(tmax, 32));
        const float mnew = fmaxf(mrun, tmax);
        const float fac = __expf(mrun - mnew);
        float psum = 0.f;
        #pragma unroll
        for (int kf = 0; kf < 4; ++kf)
            #pragma unroll
            for (int rg = 0; rg < 4; ++rg) {
                const float p = __expf(sacc[kf][rg] - mnew);
                sacc[kf][rg] = p;
                psum += p;
            }
        psum += __shfl_xor(psum, 16);
        psum += __shfl_xor(psum, 32);
        lrun = lrun * fac + psum;
        mrun = mnew;
        #pragma unroll
        for (int d = 0; d < 4; ++d) accO[d] *= fac;

        char* ptw = (char*)&PTs[w][0];
        #pragma unroll
        for (int kf = 0; kf < 4; ++kf) {
            u32x2 pk;
            pk[0] = pack2(sacc[kf][0], sacc[kf][1]);
            pk[1] = pack2(sacc[kf][2], sacc[kf][3]);
            *(u32x2*)(ptw + lq * 128 +
                      (((kf * 2 + (g >> 1)) ^ (lq & 7)) * 16) + (g & 1) * 8) = pk;
        }
        __builtin_amdgcn_s_setprio(1);
        #pragma unroll
        for (int kh = 0; kh < 2; ++kh) {
            const s16x8 pb = *(const s16x8*)(ptw + lq * 128 +
                                             (((kh * 4 + g) ^ (lq & 7)) * 16));
            #pragma unroll
            for (int df = 0; df < 4; ++df) {
                const int row = df * 16 + lq;
                const s16x8 vf = *(const s16x8*)((const char*)&VTs[cur][0] + row * 128 +
                                                 (((kh * 4 + g) ^ (row & 7)) * 16));
                accO[df] = __builtin_amdgcn_mfma_f32_16x16x32_bf16(vf, pb, accO[df], 0, 0, 0);
            }
        }
        __builtin_amdgcn_s_setprio(0);
        asm volatile("s_waitcnt vmcnt(0)" ::: "memory");
        __syncthreads();
    }

    const float inv = 1.0f / lrun;
    unsigned short* orow = sab + ((size_t)(b * S_ + i)) * D_ + hh * 64;
    #pragma unroll
    for (int df = 0; df < 4; ++df) {
        u32x2 pk;
        pk[0] = pack2(accO[df][0] * inv, accO[df][1] * inv);
        pk[1] = pack2(accO[df][2] * inv, accO[df][3] * inv);
        *(u32x2*)(orow + df * 16 + g * 4) = pk;
    }
}

// ---------------------------------------------------------------------------
__global__ __launch_bounds__(256) void embed_kernel(
    const int* __restrict__ x, const int* __restrict__ ign,
    const float* __restrict__ emb, const float* __restrict__ pos,
    float* __restrict__ h, unsigned short* __restrict__ hbf)
{
    const int row = blockIdx.x;
    const int s = row & (S_ - 1);
    const int tok = x[row];
    const float keep = (ign[row] == 0) ? 1.0f : 0.0f;
    const float* er = emb + (size_t)tok * D_;
    const float* pr = pos + (size_t)s * D_;
    float* hr = h + (size_t)row * D_;
    unsigned short* hb = hbf + (size_t)row * D_;
    for (int d = threadIdx.x; d < D_; d += 256) {
        const float t = er[d] + pr[d] * keep;
        hr[d] = t;
        hb[d] = f2bf(t);
    }
}

// ---------------------------------------------------------------------------
// out = LN(X + Y0)            (mode 0)
// out = LN(X + gelu(Y0 + Y1)) (mode 1, W2 split-K partials; bias in Y0)
// out = LN(X + Y0 + Y1)       (mode 2, Wo split-K partials; bias in Y0)
// ---------------------------------------------------------------------------
__global__ __launch_bounds__(256) void add_ln_kernel(
    const float* __restrict__ X, const float* __restrict__ Y0,
    const float* __restrict__ Y1, float* __restrict__ out,
    unsigned short* __restrict__ outbf, int mode)
{
    const int row = blockIdx.x * 4 + (threadIdx.x >> 6);
    const int l = threadIdx.x & 63;
    const float4* xr = (const float4*)(X + (size_t)row * D_);
    const float4* y0 = (const float4*)(Y0 + (size_t)row * D_);
    const float4* y1 = (const float4*)(Y1 + (size_t)row * D_);
    float4 t[3];
    float s0 = 0.f;
    #pragma unroll
    for (int k = 0; k < 3; ++k) {
        const float4 a = xr[k * 64 + l];
        float4 b = y0[k * 64 + l];
        if (mode != 0) {
            const float4 c = y1[k * 64 + l];
            b.x += c.x; b.y += c.y; b.z += c.z; b.w += c.w;
        }
        if (mode == 1) {
            b.x = 0.5f * b.x * (1.0f + erff(b.x * 0.70710678118654752f));
            b.y = 0.5f * b.y * (1.0f + erff(b.y * 0.70710678118654752f));
            b.z = 0.5f * b.z * (1.0f + erff(b.z * 0.70710678118654752f));
            b.w = 0.5f * b.w * (1.0f + erff(b.w * 0.70710678118654752f));
        }
        t[k].x = a.x + b.x; t[k].y = a.y + b.y;
        t[k].z = a.z + b.z; t[k].w = a.w + b.w;
        s0 += t[k].x + t[k].y + t[k].z + t[k].w;
    }
    #pragma unroll
    for (int o = 32; o; o >>= 1) s0 += __shfl_xor(s0, o);
    const float mu = s0 * (1.0f / D_);
    float s1 = 0.f;
    #pragma unroll
    for (int k = 0; k < 3; ++k) {
        t[k].x -= mu; t[k].y -= mu; t[k].z -= mu; t[k].w -= mu;
        s1 += t[k].x * t[k].x + t[k].y * t[k].y + t[k].z * t[k].z + t[k].w * t[k].w;
    }
    #pragma unroll
    for (int o = 32; o; o >>= 1) s1 += __shfl_xor(s1, o);
    const float inv = 1.0f / sqrtf(s1 * (1.0f / D_));
    float4* orow = (float4*)(out + (size_t)row * D_);
    u32x2* obf = (u32x2*)(outbf + (size_t)row * D_);
    #pragma unroll
    for (int k = 0; k < 3; ++k) {
        float4 r;
        r.x = t[k].x * inv; r.y = t[k].y * inv;
        r.z = t[k].z * inv; r.w = t[k].w * inv;
        orow[k * 64 + l] = r;
        u32x2 pk; pk[0] = pack2(r.x, r.y); pk[1] = pack2(r.z, r.w);
        obf[k * 64 + l] = pk;
    }
}

// ---------------------------------------------------------------------------
extern "C" void kernel_launch(void* const* d_in, const int* in_sizes, int n_in,
                              void* d_out, int out_size, void* d_ws, size_t ws_size,
                              hipStream_t stream)
{
    const int*   x    = (const int*)d_in[0];
    const int*   ign  = (const int*)d_in[1];
    const float* emb  = (const float*)d_in[2];
    const float* pos  = (const float*)d_in[3];
    const float* Wq   = (const float*)d_in[4];
    const float* bq   = (const float*)d_in[5];
    const float* Wk   = (const float*)d_in[6];
    const float* bk   = (const float*)d_in[7];
    const float* Wv   = (const float*)d_in[8];
    const float* bv   = (const float*)d_in[9];
    const float* Wo   = (const float*)d_in[10];
    const float* bo   = (const float*)d_in[11];
    const float* W1   = (const float*)d_in[12];
    const float* b1   = (const float*)d_in[13];
    const float* W2   = (const float*)d_in[14];
    const float* b2   = (const float*)d_in[15];
    const float* Wout = (const float*)d_in[16];
    const float* bout = (const float*)d_in[17];
    float* outp = (float*)d_out;

    const size_t RC = (size_t)M_ * D_;        // 1572864
    const size_t F1 = (size_t)M_ * DH_;       // 6291456
    const size_t WH = (size_t)H_ * 64 * D_;   // 589824
    const size_t WF = (size_t)D_ * DH_;       // 2359296
    const size_t WOUTE = (size_t)V_ * D_;     // 24576000

    char* wsp = (char*)d_ws;
    size_t wsleft = ws_size;
    char* dop = (char*)d_out;
    auto alloc = [&](size_t bytes, bool must_ws) -> void* {
        bytes = (bytes + 255) & ~(size_t)255;
        if (wsleft >= bytes) { void* p = wsp; wsp += bytes; wsleft -= bytes; return p; }
        if (must_ws) return nullptr;
        void* p = dop; dop += bytes; return p;
    };

    unsigned short* hbf   = (unsigned short*)alloc(RC * 2, true);
    unsigned short* woutT = (unsigned short*)alloc(WOUTE * 2, true);
    float* h    = (float*)alloc(RC * 4, false);
    float* z    = (float*)alloc(RC * 4, false);
    float* tmp  = (float*)alloc(RC * 4, false);
    float* tmp1 = (float*)alloc(RC * 4, false);
    unsigned short* zbf   = (unsigned short*)alloc(RC * 2, false);
    unsigned short* sabbf = (unsigned short*)alloc(RC * 2, false);
    unsigned short* qbf   = (unsigned short*)alloc(RC * 2, false);
    unsigned short* kbf   = (unsigned short*)alloc(RC * 2, false);
    unsigned short* vtb   = (unsigned short*)alloc(RC * 2, false);
    unsigned short* f1bf  = (unsigned short*)alloc(F1 * 2, false);
    unsigned short* wqT = (unsigned short*)alloc(L_ * WH * 2, false);
    unsigned short* wkT = (unsigned short*)alloc(L_ * WH * 2, false);
    unsigned short* wvT = (unsigned short*)alloc(L_ * WH * 2, false);
    unsigned short* woT = (unsigned short*)alloc(L_ * WH * 2, false);
    unsigned short* w1T = (unsigned short*)alloc(L_ * WF * 2, false);
    unsigned short* w2T = (unsigned short*)alloc(L_ * WF * 2, false);

    embed_kernel<<<M_, 256, 0, stream>>>(x, ign, emb, pos, h, hbf);

    // One-time weight transposes (QKV merged)
    wtr3_kernel<<<dim3(1, 12, 72), 256, 0, stream>>>(Wq, Wk, Wv, wqT, wkT, wvT);
    wtr_kernel<<<dim3(12, 12, L_), 256, 0, stream>>>(Wo, woT, D_, D_);
    wtr_kernel<<<dim3(48, 12, L_), 256, 0, stream>>>(W1, w1T, D_, DH_);
    wtr_kernel<<<dim3(12, 48, L_), 256, 0, stream>>>(W2, w2T, DH_, D_);
    if (woutT)
        wtr_kernel<<<dim3(V_ / 64, 12, 1), 256, 0, stream>>>(Wout, woutT, D_, V_);

    for (int l = 0; l < L_; ++l) {
        gemm_qk64n<<<dim3(12, 32, 2), 256, 0, stream>>>(
            hbf, wqT + l * WH, wkT + l * WH, bq + l * 768, bk + l * 768, qbf, kbf);
        gemm_v64<<<dim3(6, 32), 256, 0, stream>>>(
            hbf, wvT + l * WH, bv + l * 768, vtb);

        fattn_kernel<<<dim3(S_ / 64, H_, B_), 256, 0, stream>>>(
            qbf, kbf, vtb, ign, sabbf);

        gemm_wosk<<<dim3(6, 32, 2), 256, 0, stream>>>(
            sabbf, woT + l * WH, bo + l * D_, tmp, tmp1);
        add_ln_kernel<<<M_ / 4, 256, 0, stream>>>(h, tmp, tmp1, z, zbf, 2);

        gemm_bt64<<<dim3(24, 32), 256, 0, stream>>>(
            zbf, w1T + l * WF, b1 + l * DH_, f1bf, DH_, D_, 2);
        gemm_w2sk<<<dim3(6, 32, 2), 256, 0, stream>>>(
            f1bf, w2T + l * WF, b2 + l * D_, tmp, tmp1);
        add_ln_kernel<<<M_ / 4, 256, 0, stream>>>(z, tmp, tmp1, h, hbf, 1);
    }

    if (woutT)
        gemm_deep<<<dim3(V_ / 256, M_ / 256), 512, 0, stream>>>(
            hbf, woutT, bout, outp, V_, D_);
    else
        gemm_f32b<<<dim3(V_ / 128, M_ / 128), 256, 0, stream>>>(
            hbf, Wout, bout, outp, V_, D_);
}

// Round 15
// 443.544 us; speedup vs baseline: 1.0569x; 1.0569x over previous
//
#include <hip/hip_runtime.h>
#include <math.h>

static constexpr int L_ = 2, H_ = 12, D_ = 768, DH_ = 3072, V_ = 32000,
                     S_ = 1024, B_ = 2;
static constexpr int M_ = B_ * S_;  // 2048 token rows

typedef __attribute__((ext_vector_type(4))) float f32x4;
typedef __attribute__((ext_vector_type(8))) short s16x8;   // 8 bf16 = 4 VGPR
typedef __attribute__((ext_vector_type(2))) unsigned int u32x2;
typedef __attribute__((ext_vector_type(4))) unsigned int u32x4;

__device__ __forceinline__ unsigned short f2bf(float f) {
    unsigned u = __builtin_bit_cast(unsigned, f);
    u = (u + 0x7FFFu + ((u >> 16) & 1u)) >> 16;   // RTNE
    return (unsigned short)u;
}
__device__ __forceinline__ unsigned pack2(float a, float b) {
    return (unsigned)f2bf(a) | ((unsigned)f2bf(b) << 16);
}

__device__ __forceinline__ void gld16(const void* g, void* l) {
    __builtin_amdgcn_global_load_lds(
        (const __attribute__((address_space(1))) unsigned int*)g,
        (__attribute__((address_space(3))) unsigned int*)l, 16, 0, 0);
}

// ---------------------------------------------------------------------------
// Weight transpose: in [K][N] fp32 (mat z at z*K*N) -> out [N][K] bf16.
// ---------------------------------------------------------------------------
__global__ __launch_bounds__(256) void wtr_kernel(
    const float* __restrict__ in, unsigned short* __restrict__ out, int K, int N)
{
    __shared__ unsigned short t[64 * 68];
    const size_t mo = (size_t)blockIdx.z * K * N;
    in  += mo; out += mo;
    const int n0 = blockIdx.x * 64, k0 = blockIdx.y * 64;
    const int tid = threadIdx.x;
    const int kr = tid >> 2, nc = (tid & 3) * 16;
    const float* src = in + (size_t)(k0 + kr) * N + n0 + nc;
    #pragma unroll
    for (int j = 0; j < 4; ++j) {
        const float4 v = *(const float4*)(src + j * 4);
        *(u32x2*)&t[kr * 68 + nc + j * 4] = (u32x2){pack2(v.x, v.y), pack2(v.z, v.w)};
    }
    __syncthreads();
    const int nr = tid >> 2, kc = (tid & 3) * 16;
    unsigned short v16[16];
    #pragma unroll
    for (int j = 0; j < 16; ++j) v16[j] = t[(kc + j) * 68 + nr];
    unsigned short* dst = out + (size_t)(n0 + nr) * K + k0 + kc;
    ((u32x4*)dst)[0] = *(u32x4*)&v16[0];
    ((u32x4*)dst)[1] = *(u32x4*)&v16[8];
}

// Merged QKV transpose: 3 matrices x L_*H_ head-slices, one launch.
__global__ __launch_bounds__(256) void wtr3_kernel(
    const float* __restrict__ Wq, const float* __restrict__ Wk,
    const float* __restrict__ Wv, unsigned short* __restrict__ oq,
    unsigned short* __restrict__ ok, unsigned short* __restrict__ ov)
{
    __shared__ unsigned short t[64 * 68];
    const int z = blockIdx.z;
    const int which = z / 24, zz = z - which * 24;
    const float* in = (which == 0) ? Wq : (which == 1) ? Wk : Wv;
    unsigned short* out = (which == 0) ? oq : (which == 1) ? ok : ov;
    const size_t mo = (size_t)zz * D_ * 64;
    in += mo; out += mo;
    const int k0 = blockIdx.y * 64;
    const int tid = threadIdx.x;
    const int kr = tid >> 2, nc = (tid & 3) * 16;
    const float* src = in + (size_t)(k0 + kr) * 64 + nc;
    #pragma unroll
    for (int j = 0; j < 4; ++j) {
        const float4 v = *(const float4*)(src + j * 4);
        *(u32x2*)&t[kr * 68 + nc + j * 4] = (u32x2){pack2(v.x, v.y), pack2(v.z, v.w)};
    }
    __syncthreads();
    const int nr = tid >> 2, kc = (tid & 3) * 16;
    unsigned short v16[16];
    #pragma unroll
    for (int j = 0; j < 16; ++j) v16[j] = t[(kc + j) * 68 + nr];
    unsigned short* dst = out + (size_t)nr * D_ + k0 + kc;
    ((u32x4*)dst)[0] = *(u32x4*)&v16[0];
    ((u32x4*)dst)[1] = *(u32x4*)&v16[8];
}

__device__ __forceinline__ void xcd_decode(int& bx, int& by) {
    const int gx = gridDim.x, gy = gridDim.y;
    const int nwg = gx * gy;
    const int flat = blockIdx.y * gx + blockIdx.x;
    const int s = (flat & 7) * (nwg >> 3) + (flat >> 3);
    bx = s / gy;
    by = s % gy;
}

// ---------------------------------------------------------------------------
// 64x128 tile GEMM — workhorse for mid-size GEMMs. 256 threads = 4 waves 1x4;
// per-wave 64x32, acc 4x2. LDS 24 KiB -> 5+ blocks/CU. Granule-XOR layout.
// act 0: f32+bias. 1: f32+bias+gelu. 2: bf16+bias [M][N].
// 3: V^T bf16+bias [B][H][64][S] (LDS-bounced coalesced). 4: f32 raw (splitK).
// ---------------------------------------------------------------------------
__device__ __forceinline__ void bt64_body(
    const unsigned short* __restrict__ A, const unsigned short* __restrict__ BT,
    const float* __restrict__ bias, void* __restrict__ Cp,
    int N, int K, int act, int k0off, int klen, int bx, int by)
{
    __shared__ unsigned short AB[12288];   // As = AB (8KB), Bs = AB+4096 (16KB)
    unsigned short* As = AB;
    unsigned short* Bs = AB + 4096;
    const int tid = threadIdx.x;
    const int l = tid & 63, w = tid >> 6;
    const int lq = l & 15, lg = l >> 4;
    const int brow = by * 64, bn = bx * 128;

    f32x4 acc[4][2];
    #pragma unroll
    for (int i = 0; i < 4; ++i)
        #pragma unroll
        for (int j = 0; j < 2; ++j) acc[i][j] = (f32x4)0.f;

    const int arow = tid >> 3;                    // 0..31
    const int aq   = (tid & 7) ^ (arow & 7);
    const unsigned short* Abase = A  + (size_t)(brow + arow) * K + k0off + aq * 8;
    const unsigned short* Bbase = BT + (size_t)(bn   + arow) * K + k0off + aq * 8;

    for (int k0 = 0; k0 < klen; k0 += 64) {
        #pragma unroll
        for (int r = 0; r < 2; ++r)
            gld16(Abase + (size_t)r * 32 * K + k0, (char*)As + r * 4096 + tid * 16);
        #pragma unroll
        for (int r = 0; r < 4; ++r)
            gld16(Bbase + (size_t)r * 32 * K + k0, (char*)Bs + r * 4096 + tid * 16);
        __syncthreads();

        #pragma unroll
        for (int kk = 0; kk < 2; ++kk) {
            s16x8 af[4], bf[2];
            #pragma unroll
            for (int mf = 0; mf < 4; ++mf) {
                const int row = mf * 16 + lq;
                const int gg  = (kk * 4 + lg) ^ (row & 7);
                af[mf] = *(const s16x8*)((const char*)As + row * 128 + gg * 16);
            }
            #pragma unroll
            for (int nf = 0; nf < 2; ++nf) {
                const int col = w * 32 + nf * 16 + lq;
                const int gg  = (kk * 4 + lg) ^ (col & 7);
                bf[nf] = *(const s16x8*)((const char*)Bs + col * 128 + gg * 16);
            }
            #pragma unroll
            for (int mf = 0; mf < 4; ++mf)
                #pragma unroll
                for (int nf = 0; nf < 2; ++nf)
                    acc[mf][nf] = __builtin_amdgcn_mfma_f32_16x16x32_bf16(
                        af[mf], bf[nf], acc[mf][nf], 0, 0, 0);
        }
        __syncthreads();
    }

    if (act == 3) {
        #pragma unroll
        for (int nf = 0; nf < 2; ++nf) {
            const int c = w * 32 + nf * 16 + lq;
            const float bb = bias[bn + c];
            #pragma unroll
            for (int mf = 0; mf < 4; ++mf) {
                const int srel = mf * 16 + lg * 4;
                u32x2 pk;
                pk[0] = pack2(acc[mf][nf][0] + bb, acc[mf][nf][1] + bb);
                pk[1] = pack2(acc[mf][nf][2] + bb, acc[mf][nf][3] + bb);
                const int byo = (c * 128 + srel * 2) ^ ((c & 7) << 4);
                *(u32x2*)((char*)AB + byo) = pk;
            }
        }
        __syncthreads();
        const int row = tid >> 1, half = tid & 1;
        const int gcf = bn + row;
        const int head = gcf >> 6, d = gcf & 63;
        const int b = brow >> 10;
        const int sb = (brow & (S_ - 1)) + half * 32;
        unsigned short* dst = (unsigned short*)Cp +
            (((size_t)b * H_ + head) * 64 + d) * S_ + sb;
        #pragma unroll
        for (int u = 0; u < 4; ++u) {
            const int byo = (row * 128 + half * 64 + u * 16) ^ ((row & 7) << 4);
            ((u32x4*)dst)[u] = *(const u32x4*)((const char*)AB + byo);
        }
        return;
    }
    #pragma unroll
    for (int nf = 0; nf < 2; ++nf) {
        const int gcol = bn + w * 32 + nf * 16 + lq;
        const float bb = (act == 4) ? 0.f : bias[gcol];
        #pragma unroll
        for (int mf = 0; mf < 4; ++mf)
            #pragma unroll
            for (int rg = 0; rg < 4; ++rg) {
                const int grow = brow + mf * 16 + lg * 4 + rg;
                float vv = acc[mf][nf][rg] + bb;
                if (act == 1) vv = 0.5f * vv * (1.0f + erff(vv * 0.70710678118654752f));
                if (act == 2)
                    ((unsigned short*)Cp)[(size_t)grow * N + gcol] = f2bf(vv);
                else
                    ((float*)Cp)[(size_t)grow * N + gcol] = vv;
            }
    }
}

__global__ __launch_bounds__(256) void gemm_bt64(
    const unsigned short* __restrict__ A, const unsigned short* __restrict__ BT,
    const float* __restrict__ bias, void* __restrict__ C, int N, int K, int act)
{
    int bx, by; xcd_decode(bx, by);
    bt64_body(A, BT, bias, C, N, K, act, 0, K, bx, by);
}

// QKV, 64-row tiles: grid (6, 32, 3). act2 for q,k; act3 (V^T) for v.
__global__ __launch_bounds__(256) void gemm_qkv64(
    const unsigned short* __restrict__ A,
    const unsigned short* __restrict__ qT, const unsigned short* __restrict__ kT,
    const unsigned short* __restrict__ vT,
    const float* __restrict__ bq, const float* __restrict__ bk, const float* __restrict__ bv,
    unsigned short* __restrict__ q, unsigned short* __restrict__ k,
    unsigned short* __restrict__ v)
{
    const unsigned short* BT; const float* bi; unsigned short* C; int act;
    if (blockIdx.z == 0)      { BT = qT; bi = bq; C = q; act = 2; }
    else if (blockIdx.z == 1) { BT = kT; bi = bk; C = k; act = 2; }
    else                      { BT = vT; bi = bv; C = v; act = 3; }
    int bx, by; xcd_decode(bx, by);
    bt64_body(A, BT, bi, C, 768, 768, act, 0, 768, bx, by);
}

// W2 split-K: grid (6, 32, 2). z=0 -> partial0 (with bias), z=1 -> partial1 raw.
__global__ __launch_bounds__(256) void gemm_w2sk(
    const unsigned short* __restrict__ A, const unsigned short* __restrict__ BT,
    const float* __restrict__ bias, float* __restrict__ C0, float* __restrict__ C1)
{
    int bx, by; xcd_decode(bx, by);
    if (blockIdx.z == 0)
        bt64_body(A, BT, bias, C0, 768, DH_, 0, 0, 1536, bx, by);
    else
        bt64_body(A, BT, bias, C1, 768, DH_, 4, 1536, 1536, bx, by);
}

// Wo split-K: grid (6, 32, 2). K=768 halves.
__global__ __launch_bounds__(256) void gemm_wosk(
    const unsigned short* __restrict__ A, const unsigned short* __restrict__ BT,
    const float* __restrict__ bias, float* __restrict__ C0, float* __restrict__ C1)
{
    int bx, by; xcd_decode(bx, by);
    if (blockIdx.z == 0)
        bt64_body(A, BT, bias, C0, 768, 768, 0, 0, 384, bx, by);
    else
        bt64_body(A, BT, bias, C1, 768, 768, 4, 384, 384, bx, by);
}

// ---------------------------------------------------------------------------
// 256x256 8-wave GEMM for the logits matmul (round-8 schedule, best of 5).
// ---------------------------------------------------------------------------
__global__ __launch_bounds__(512, 2) void gemm_deep(
    const unsigned short* __restrict__ A, const unsigned short* __restrict__ BT,
    const float* __restrict__ bias, float* __restrict__ C, int N, int K)
{
    __shared__ char lds[131072];   // A: c*32768; B: 65536 + c*32768
    const int tid = threadIdx.x;
    const int l = tid & 63, w = tid >> 6;
    const int wr = w >> 2, wc = w & 3;
    const int lq = l & 15, lg = l >> 4;

    int bx, by;
    {
        const int gx = gridDim.x, gy = gridDim.y;
        const int nwg = gx * gy;
        const int flat = blockIdx.y * gx + blockIdx.x;
        const int s = (flat & 7) * (nwg >> 3) + (flat >> 3);
        bx = s / gy; by = s % gy;
    }
    const int brow = by * 256, bn = bx * 256;
    const int NT = K >> 6;   // 12

    const int srow = (w << 3) + (l >> 3);        // 0..63
    const int sgr  = (l & 7) ^ (l >> 3);
    const size_t soff = (size_t)srow * K + sgr * 8;
    const unsigned short* Ag = A  + (size_t)brow * K + soff;
    const unsigned short* Bg = BT + (size_t)bn   * K + soff;
    const size_t r64  = (size_t)64 * K;
    const size_t r128 = (size_t)128 * K;
    char* const dA = lds + w * 1024;
    char* const dB = lds + 65536 + w * 1024;

#define STG_A(CB, HF, KT) do {                                                   \
    gld16(Ag + (size_t)(HF) * r128 + (size_t)(KT) * 64,                          \
          dA + (CB) * 32768 + (HF) * 16384);                                     \
    gld16(Ag + (size_t)(HF) * r128 + r64 + (size_t)(KT) * 64,                    \
          dA + (CB) * 32768 + (HF) * 16384 + 8192); } while (0)
#define STG_B(CB, HF, KT) do {                                                   \
    gld16(Bg + (size_t)(HF) * r128 + (size_t)(KT) * 64,                          \
          dB + (CB) * 32768 + (HF) * 16384);                                     \
    gld16(Bg + (size_t)(HF) * r128 + r64 + (size_t)(KT) * 64,                    \
          dB + (CB) * 32768 + (HF) * 16384 + 8192); } while (0)

    f32x4 acc[8][4];
    #pragma unroll
    for (int i = 0; i < 8; ++i)
        #pragma unroll
        for (int j = 0; j < 4; ++j) acc[i][j] = (f32x4)0.f;

    STG_A(0, 0, 0); STG_A(0, 1, 0); STG_B(0, 0, 0); STG_B(0, 1, 0);
    STG_A(1, 0, 1); STG_B(1, 0, 1);
    asm volatile("s_waitcnt vmcnt(4)" ::: "memory");
    __builtin_amdgcn_s_barrier();

    for (int t = 0; t < NT; ++t) {
        const int c = t & 1;
        const char* Ab = lds + c * 32768;
        const char* Bb = lds + 65536 + c * 32768;
        s16x8 af[4], bf[4];

        #pragma unroll
        for (int mf = 0; mf < 4; ++mf) {
            const int row = wr * 128 + mf * 16 + lq;
            af[mf] = *(const s16x8*)(Ab + row * 128 + ((lg ^ (row & 7)) << 4));
        }
        #pragma unroll
        for (int nf = 0; nf < 4; ++nf) {
            const int col = wc * 64 + nf * 16 + lq;
            bf[nf] = *(const s16x8*)(Bb + col * 128 + ((lg ^ (col & 7)) << 4));
        }
        if (t + 1 < NT) STG_A(c ^ 1, 1, t + 1);
        asm volatile("s_waitcnt lgkmcnt(0)" ::: "memory");
        __builtin_amdgcn_sched_barrier(0);
        __builtin_amdgcn_s_barrier();
        __builtin_amdgcn_s_setprio(1);
        #pragma unroll
        for (int mf = 0; mf < 4; ++mf)
            #pragma unroll
            for (int nf = 0; nf < 4; ++nf)
                acc[mf][nf] = __builtin_amdgcn_mfma_f32_16x16x32_bf16(
                    af[mf], bf[nf], acc[mf][nf], 0, 0, 0);
        __builtin_amdgcn_s_setprio(0);
        __builtin_amdgcn_s_barrier();

        #pragma unroll
        for (int mf = 0; mf < 4; ++mf) {
            const int row = wr * 128 + (mf + 4) * 16 + lq;
            af[mf] = *(const s16x8*)(Ab + row * 128 + ((lg ^ (row & 7)) << 4));
        }
        if (t + 1 < NT) STG_B(c ^ 1, 1, t + 1);
        asm volatile("s_waitcnt lgkmcnt(0)" ::: "memory");
        __builtin_amdgcn_sched_barrier(0);
        __builtin_amdgcn_s_barrier();
        __builtin_amdgcn_s_setprio(1);
        #pragma unroll
        for (int mf = 0; mf < 4; ++mf)
            #pragma unroll
            for (int nf = 0; nf < 4; ++nf)
                acc[mf + 4][nf] = __builtin_amdgcn_mfma_f32_16x16x32_bf16(
                    af[mf], bf[nf], acc[mf + 4][nf], 0, 0, 0);
        __builtin_amdgcn_s_setprio(0);
        __builtin_amdgcn_s_barrier();

        #pragma unroll
        for (int mf = 0; mf < 4; ++mf) {
            const int row = wr * 128 + mf * 16 + lq;
            af[mf] = *(const s16x8*)(Ab + row * 128 + (((4 + lg) ^ (row & 7)) << 4));
        }
        #pragma unroll
        for (int nf = 0; nf < 4; ++nf) {
            const int col = wc * 64 + nf * 16 + lq;
            bf[nf] = *(const s16x8*)(Bb + col * 128 + (((4 + lg) ^ (col & 7)) << 4));
        }
        asm volatile("s_waitcnt lgkmcnt(0)" ::: "memory");
        __builtin_amdgcn_sched_barrier(0);
        __builtin_amdgcn_s_barrier();
        __builtin_amdgcn_s_setprio(1);
        #pragma unroll
        for (int mf = 0; mf < 4; ++mf)
            #pragma unroll
            for (int nf = 0; nf < 4; ++nf)
                acc[mf][nf] = __builtin_amdgcn_mfma_f32_16x16x32_bf16(
                    af[mf], bf[nf], acc[mf][nf], 0, 0, 0);
        __builtin_amdgcn_s_setprio(0);
        __builtin_amdgcn_s_barrier();

        #pragma unroll
        for (int mf = 0; mf < 4; ++mf) {
            const int row = wr * 128 + (mf + 4) * 16 + lq;
            af[mf] = *(const s16x8*)(Ab + row * 128 + (((4 + lg) ^ (row & 7)) << 4));
        }
        asm volatile("s_waitcnt lgkmcnt(0)" ::: "memory");
        __builtin_amdgcn_sched_barrier(0);
        __builtin_amdgcn_s_barrier();
        __builtin_amdgcn_s_setprio(1);
        #pragma unroll
        for (int mf = 0; mf < 4; ++mf)
            #pragma unroll
            for (int nf = 0; nf < 4; ++nf)
                acc[mf + 4][nf] = __builtin_amdgcn_mfma_f32_16x16x32_bf16(
                    af[mf], bf[nf], acc[mf + 4][nf], 0, 0, 0);
        __builtin_amdgcn_s_setprio(0);

        if (t + 2 < NT) {
            STG_A(c, 0, t + 2); STG_B(c, 0, t + 2);
            asm volatile("s_waitcnt vmcnt(4)" ::: "memory");
            __builtin_amdgcn_s_barrier();
        } else if (t + 1 < NT) {
            asm volatile("s_waitcnt vmcnt(0)" ::: "memory");
            __builtin_amdgcn_s_barrier();
        }
    }
#undef STG_A
#undef STG_B

    #pragma unroll
    for (int nf = 0; nf < 4; ++nf) {
        const int gcol = bn + wc * 64 + nf * 16 + lq;
        const float bb = bias[gcol];
        #pragma unroll
        for (int mf = 0; mf < 8; ++mf)
            #pragma unroll
            for (int rg = 0; rg < 4; ++rg) {
                const int grow = brow + wr * 128 + mf * 16 + lg * 4 + rg;
                C[(size_t)grow * N + gcol] = acc[mf][nf][rg] + bb;
            }
    }
}

// ---------------------------------------------------------------------------
// Fallback GEMM (fp32 B in [K][N]) — only if ws can't hold transposed Wout.
// ---------------------------------------------------------------------------
__global__ __launch_bounds__(256) void gemm_f32b(
    const unsigned short* __restrict__ A, const float* __restrict__ B,
    const float* __restrict__ bias, float* __restrict__ C, int N, int K)
{
    __shared__ unsigned short As[8192];
    __shared__ unsigned short Bs[8192];
    const int tid = threadIdx.x;
    const int l   = tid & 63, wid = tid >> 6;
    const int wr  = wid >> 1, wc = wid & 1;
    const int brow = blockIdx.y * 128, bn = blockIdx.x * 128;
    f32x4 acc[4][4];
    #pragma unroll
    for (int i = 0; i < 4; ++i)
        #pragma unroll
        for (int j = 0; j < 4; ++j) acc[i][j] = (f32x4)0.f;
    const int arow = tid >> 3;
    const int aq   = (tid & 7) ^ (arow & 7);
    const int bkq  = tid >> 5, bnq = tid & 31;
    for (int k0 = 0; k0 < K; k0 += 64) {
        #pragma unroll
        for (int r = 0; r < 4; ++r)
            gld16(A + (size_t)(brow + r * 32 + arow) * K + k0 + aq * 8,
                  (char*)As + r * 4096 + wid * 1024);
        #pragma unroll
        for (int r = 0; r < 2; ++r) {
            const int kb = r * 32 + bkq * 4;
            const float* pp = B + (size_t)(k0 + kb) * N + bn + bnq * 4;
            const float4 v0 = *(const float4*)(pp);
            const float4 v1 = *(const float4*)(pp + N);
            const float4 v2 = *(const float4*)(pp + 2 * (size_t)N);
            const float4 v3 = *(const float4*)(pp + 3 * (size_t)N);
            const int g = kb >> 3, bytek = (kb & 4) * 2;
            const float* f0 = (const float*)&v0; const float* f1 = (const float*)&v1;
            const float* f2 = (const float*)&v2; const float* f3 = (const float*)&v3;
            #pragma unroll
            for (int i = 0; i < 4; ++i) {
                const int n = bnq * 4 + i;
                char* dst = (char*)Bs + n * 128 + ((g ^ (n & 7)) * 16) + bytek;
                *(u32x2*)dst = (u32x2){pack2(f0[i], f1[i]), pack2(f2[i], f3[i])};
            }
        }
        __syncthreads();
        #pragma unroll
        for (int kk = 0; kk < 2; ++kk) {
            s16x8 af[4], bf[4];
            #pragma unroll
            for (int mf = 0; mf < 4; ++mf) {
                const int row = wr * 64 + mf * 16 + (l & 15);
                const int gg  = (kk * 4 + (l >> 4)) ^ (row & 7);
                af[mf] = *(const s16x8*)((const char*)As + row * 128 + gg * 16);
            }
            #pragma unroll
            for (int nf = 0; nf < 4; ++nf) {
                const int col = wc * 64 + nf * 16 + (l & 15);
                const int gg  = (kk * 4 + (l >> 4)) ^ (col & 7);
                bf[nf] = *(const s16x8*)((const char*)Bs + col * 128 + gg * 16);
            }
            #pragma unroll
            for (int mf = 0; mf < 4; ++mf)
                #pragma unroll
                for (int nf = 0; nf < 4; ++nf)
                    acc[mf][nf] = __builtin_amdgcn_mfma_f32_16x16x32_bf16(
                        af[mf], bf[nf], acc[mf][nf], 0, 0, 0);
        }
        __syncthreads();
    }
    const int lr = l >> 4, lc = l & 15;
    #pragma unroll
    for (int nf = 0; nf < 4; ++nf) {
        const int gcol = bn + wc * 64 + nf * 16 + lc;
        const float bb = bias[gcol];
        #pragma unroll
        for (int mf = 0; mf < 4; ++mf)
            #pragma unroll
            for (int rg = 0; rg < 4; ++rg) {
                const int grow = brow + wr * 64 + mf * 16 + lr * 4 + rg;
                C[(size_t)grow * N + gcol] = acc[mf][nf][rg] + bb;
            }
    }
}

// ---------------------------------------------------------------------------
// Flash attention v3: mask addend + setprio + dbuf + balance remap.
// ---------------------------------------------------------------------------
__global__ __launch_bounds__(256) void fattn_kernel(
    const unsigned short* __restrict__ qm, const unsigned short* __restrict__ km,
    const unsigned short* __restrict__ vt, const int* __restrict__ ign,
    unsigned short* __restrict__ sab)
{
    __shared__ unsigned short Ks[2][4096];
    __shared__ unsigned short VTs[2][4096];
    __shared__ float addvs[2][64];
    __shared__ unsigned short PTs[4][1024];

    const int hh = blockIdx.y, b = blockIdx.z;
    const int zy = b * 12 + hh;
    const int qt = (zy >= 16) ? (15 - blockIdx.x) : blockIdx.x;

    const int tid = threadIdx.x;
    const int l = tid & 63, w = tid >> 6;
    const int g = l >> 4, lq = l & 15;
    const int i = qt * 64 + w * 16 + lq;

    const size_t qgb = ((size_t)(b * S_ + i)) * D_ + hh * 64;
    const s16x8 qf0 = *(const s16x8*)(qm + qgb + g * 8);
    const s16x8 qf1 = *(const s16x8*)(qm + qgb + 32 + g * 8);

    f32x4 accO[4];
    #pragma unroll
    for (int d = 0; d < 4; ++d) accO[d] = (f32x4)0.f;
    float mrun = -1e30f, lrun = 0.f;

    const int srow = tid >> 3, sg = tid & 7;
    const size_t kbase = (size_t)(b * S_) * D_ + hh * 64;
    const size_t vbase = ((size_t)(b * H_ + hh) * 64) * S_;

    auto stage = [&](int t, int bufi) {
        const int j0 = t * 64;
        #pragma unroll
        for (int r = 0; r < 2; ++r) {
            const int row = r * 32 + srow;
            const int gsw = (sg ^ (row & 7)) * 8;
            gld16(km + kbase + (size_t)(j0 + row) * D_ + gsw,
                  (char*)&Ks[bufi][0] + (r * 256 + tid) * 16);
            gld16(vt + vbase + (size_t)row * S_ + j0 + gsw,
                  (char*)&VTs[bufi][0] + (r * 256 + tid) * 16);
        }
        if (tid < 64)
            addvs[bufi][tid] = (ign[b * S_ + j0 + tid] == 0) ? 0.f : -INFINITY;
    };

    stage(0, 0);
    asm volatile("s_waitcnt vmcnt(0) lgkmcnt(0)" ::: "memory");
    __syncthreads();

    for (int t = 0; t <= qt; ++t) {
        const int cur = t & 1;
        const int j0 = t * 64;
        if (t < qt) stage(t + 1, cur ^ 1);

        f32x4 adv[4];
        #pragma unroll
        for (int kf = 0; kf < 4; ++kf)
            adv[kf] = *(const f32x4*)&addvs[cur][kf * 16 + g * 4];

        f32x4 sacc[4];
        #pragma unroll
        for (int kf = 0; kf < 4; ++kf) sacc[kf] = (f32x4)0.f;
        __builtin_amdgcn_s_setprio(1);
        #pragma unroll
        for (int kk = 0; kk < 2; ++kk) {
            const s16x8 qv = kk ? qf1 : qf0;
            #pragma unroll
            for (int kf = 0; kf < 4; ++kf) {
                const int row = kf * 16 + lq;
                const s16x8 kv = *(const s16x8*)((const char*)&Ks[cur][0] + row * 128 +
                                                 (((kk * 4 + g) ^ (row & 7)) * 16));
                sacc[kf] = __builtin_amdgcn_mfma_f32_16x16x32_bf16(kv, qv, sacc[kf], 0, 0, 0);
            }
        }
        __builtin_amdgcn_s_setprio(0);

        float tmax = -INFINITY;
        if (t < qt) {
            #pragma unroll
            for (int kf = 0; kf < 4; ++kf)
                #pragma unroll
                for (int rg = 0; rg < 4; ++rg) {
                    const float s = fmaf(sacc[kf][rg], 0.125f, adv[kf][rg]);
                    sacc[kf][rg] = s;
                    tmax = fmaxf(tmax, s);
                }
        } else {
            #pragma unroll
            for (int kf = 0; kf < 4; ++kf)
                #pragma unroll
                for (int rg = 0; rg < 4; ++rg) {
                    const int j = j0 + kf * 16 + g * 4 + rg;
                    const float sv = sacc[kf][rg] * 0.125f;
                    const float s = (j > i) ? -INFINITY
                                  : (j == i ? sv : sv + adv[kf][rg]);
                    sacc[kf][rg] = s;
                    tmax = fmaxf(tmax, s);
                }
        }
        tmax = fmaxf(tmax, __shfl_xor(tmax, 16));
        tmax = fmaxf(tmax, __shfl_xor(tmax, 32));
        const float mnew = fmaxf(mrun, tmax);
        const float fac = __expf(mrun - mnew);
        float psum = 0.f;
        #pragma unroll
        for (int kf = 0; kf < 4; ++kf)
            #pragma unroll
            for (int rg = 0; rg < 4; ++rg) {
                const float p = __expf(sacc[kf][rg] - mnew);
                sacc[kf][rg] = p;
                psum += p;
            }
        psum += __shfl_xor(psum, 16);
        psum += __shfl_xor(psum, 32);
        lrun = lrun * fac + psum;
        mrun = mnew;
        #pragma unroll
        for (int d = 0; d < 4; ++d) accO[d] *= fac;

        char* ptw = (char*)&PTs[w][0];
        #pragma unroll
        for (int kf = 0; kf < 4; ++kf) {
            u32x2 pk;
            pk[0] = pack2(sacc[kf][0], sacc[kf][1]);
            pk[1] = pack2(sacc[kf][2], sacc[kf][3]);
            *(u32x2*)(ptw + lq * 128 +
                      (((kf * 2 + (g >> 1)) ^ (lq & 7)) * 16) + (g & 1) * 8) = pk;
        }
        __builtin_amdgcn_s_setprio(1);
        #pragma unroll
        for (int kh = 0; kh < 2; ++kh) {
            const s16x8 pb = *(const s16x8*)(ptw + lq * 128 +
                                             (((kh * 4 + g) ^ (lq & 7)) * 16));
            #pragma unroll
            for (int df = 0; df < 4; ++df) {
                const int row = df * 16 + lq;
                const s16x8 vf = *(const s16x8*)((const char*)&VTs[cur][0] + row * 128 +
                                                 (((kh * 4 + g) ^ (row & 7)) * 16));
                accO[df] = __builtin_amdgcn_mfma_f32_16x16x32_bf16(vf, pb, accO[df], 0, 0, 0);
            }
        }
        __builtin_amdgcn_s_setprio(0);
        asm volatile("s_waitcnt vmcnt(0)" ::: "memory");
        __syncthreads();
    }

    const float inv = 1.0f / lrun;
    unsigned short* orow = sab + ((size_t)(b * S_ + i)) * D_ + hh * 64;
    #pragma unroll
    for (int df = 0; df < 4; ++df) {
        u32x2 pk;
        pk[0] = pack2(accO[df][0] * inv, accO[df][1] * inv);
        pk[1] = pack2(accO[df][2] * inv, accO[df][3] * inv);
        *(u32x2*)(orow + df * 16 + g * 4) = pk;
    }
}

// ---------------------------------------------------------------------------
__global__ __launch_bounds__(256) void embed_kernel(
    const int* __restrict__ x, const int* __restrict__ ign,
    const float* __restrict__ emb, const float* __restrict__ pos,
    float* __restrict__ h, unsigned short* __restrict__ hbf)
{
    const int row = blockIdx.x;
    const int s = row & (S_ - 1);
    const int tok = x[row];
    const float keep = (ign[row] == 0) ? 1.0f : 0.0f;
    const float* er = emb + (size_t)tok * D_;
    const float* pr = pos + (size_t)s * D_;
    float* hr = h + (size_t)row * D_;
    unsigned short* hb = hbf + (size_t)row * D_;
    for (int d = threadIdx.x; d < D_; d += 256) {
        const float t = er[d] + pr[d] * keep;
        hr[d] = t;
        hb[d] = f2bf(t);
    }
}

// ---------------------------------------------------------------------------
// out = LN(X + Y0)            (mode 0)
// out = LN(X + gelu(Y0 + Y1)) (mode 1, W2 split-K partials; bias in Y0)
// out = LN(X + Y0 + Y1)       (mode 2, Wo split-K partials; bias in Y0)
// ---------------------------------------------------------------------------
__global__ __launch_bounds__(256) void add_ln_kernel(
    const float* __restrict__ X, const float* __restrict__ Y0,
    const float* __restrict__ Y1, float* __restrict__ out,
    unsigned short* __restrict__ outbf, int mode)
{
    const int row = blockIdx.x * 4 + (threadIdx.x >> 6);
    const int l = threadIdx.x & 63;
    const float4* xr = (const float4*)(X + (size_t)row * D_);
    const float4* y0 = (const float4*)(Y0 + (size_t)row * D_);
    const float4* y1 = (const float4*)(Y1 + (size_t)row * D_);
    float4 t[3];
    float s0 = 0.f;
    #pragma unroll
    for (int k = 0; k < 3; ++k) {
        const float4 a = xr[k * 64 + l];
        float4 b = y0[k * 64 + l];
        if (mode != 0) {
            const float4 c = y1[k * 64 + l];
            b.x += c.x; b.y += c.y; b.z += c.z; b.w += c.w;
        }
        if (mode == 1) {
            b.x = 0.5f * b.x * (1.0f + erff(b.x * 0.70710678118654752f));
            b.y = 0.5f * b.y * (1.0f + erff(b.y * 0.70710678118654752f));
            b.z = 0.5f * b.z * (1.0f + erff(b.z * 0.70710678118654752f));
            b.w = 0.5f * b.w * (1.0f + erff(b.w * 0.70710678118654752f));
        }
        t[k].x = a.x + b.x; t[k].y = a.y + b.y;
        t[k].z = a.z + b.z; t[k].w = a.w + b.w;
        s0 += t[k].x + t[k].y + t[k].z + t[k].w;
    }
    #pragma unroll
    for (int o = 32; o; o >>= 1) s0 += __shfl_xor(s0, o);
    const float mu = s0 * (1.0f / D_);
    float s1 = 0.f;
    #pragma unroll
    for (int k = 0; k < 3; ++k) {
        t[k].x -= mu; t[k].y -= mu; t[k].z -= mu; t[k].w -= mu;
        s1 += t[k].x * t[k].x + t[k].y * t[k].y + t[k].z * t[k].z + t[k].w * t[k].w;
    }
    #pragma unroll
    for (int o = 32; o; o >>= 1) s1 += __shfl_xor(s1, o);
    const float inv = 1.0f / sqrtf(s1 * (1.0f / D_));
    float4* orow = (float4*)(out + (size_t)row * D_);
    u32x2* obf = (u32x2*)(outbf + (size_t)row * D_);
    #pragma unroll
    for (int k = 0; k < 3; ++k) {
        float4 r;
        r.x = t[k].x * inv; r.y = t[k].y * inv;
        r.z = t[k].z * inv; r.w = t[k].w * inv;
        orow[k * 64 + l] = r;
        u32x2 pk; pk[0] = pack2(r.x, r.y); pk[1] = pack2(r.z, r.w);
        obf[k * 64 + l] = pk;
    }
}

// ---------------------------------------------------------------------------
extern "C" void kernel_launch(void* const* d_in, const int* in_sizes, int n_in,
                              void* d_out, int out_size, void* d_ws, size_t ws_size,
                              hipStream_t stream)
{
    const int*   x    = (const int*)d_in[0];
    const int*   ign  = (const int*)d_in[1];
    const float* emb  = (const float*)d_in[2];
    const float* pos  = (const float*)d_in[3];
    const float* Wq   = (const float*)d_in[4];
    const float* bq   = (const float*)d_in[5];
    const float* Wk   = (const float*)d_in[6];
    const float* bk   = (const float*)d_in[7];
    const float* Wv   = (const float*)d_in[8];
    const float* bv   = (const float*)d_in[9];
    const float* Wo   = (const float*)d_in[10];
    const float* bo   = (const float*)d_in[11];
    const float* W1   = (const float*)d_in[12];
    const float* b1   = (const float*)d_in[13];
    const float* W2   = (const float*)d_in[14];
    const float* b2   = (const float*)d_in[15];
    const float* Wout = (const float*)d_in[16];
    const float* bout = (const float*)d_in[17];
    float* outp = (float*)d_out;

    const size_t RC = (size_t)M_ * D_;        // 1572864
    const size_t F1 = (size_t)M_ * DH_;       // 6291456
    const size_t WH = (size_t)H_ * 64 * D_;   // 589824
    const size_t WF = (size_t)D_ * DH_;       // 2359296
    const size_t WOUTE = (size_t)V_ * D_;     // 24576000

    char* wsp = (char*)d_ws;
    size_t wsleft = ws_size;
    char* dop = (char*)d_out;
    auto alloc = [&](size_t bytes, bool must_ws) -> void* {
        bytes = (bytes + 255) & ~(size_t)255;
        if (wsleft >= bytes) { void* p = wsp; wsp += bytes; wsleft -= bytes; return p; }
        if (must_ws) return nullptr;
        void* p = dop; dop += bytes; return p;
    };

    unsigned short* hbf   = (unsigned short*)alloc(RC * 2, true);
    unsigned short* woutT = (unsigned short*)alloc(WOUTE * 2, true);
    float* h    = (float*)alloc(RC * 4, false);
    float* z    = (float*)alloc(RC * 4, false);
    float* tmp  = (float*)alloc(RC * 4, false);
    float* tmp1 = (float*)alloc(RC * 4, false);
    unsigned short* zbf   = (unsigned short*)alloc(RC * 2, false);
    unsigned short* sabbf = (unsigned short*)alloc(RC * 2, false);
    unsigned short* qbf   = (unsigned short*)alloc(RC * 2, false);
    unsigned short* kbf   = (unsigned short*)alloc(RC * 2, false);
    unsigned short* vtb   = (unsigned short*)alloc(RC * 2, false);
    unsigned short* f1bf  = (unsigned short*)alloc(F1 * 2, false);
    unsigned short* wqT = (unsigned short*)alloc(L_ * WH * 2, false);
    unsigned short* wkT = (unsigned short*)alloc(L_ * WH * 2, false);
    unsigned short* wvT = (unsigned short*)alloc(L_ * WH * 2, false);
    unsigned short* woT = (unsigned short*)alloc(L_ * WH * 2, false);
    unsigned short* w1T = (unsigned short*)alloc(L_ * WF * 2, false);
    unsigned short* w2T = (unsigned short*)alloc(L_ * WF * 2, false);

    embed_kernel<<<M_, 256, 0, stream>>>(x, ign, emb, pos, h, hbf);

    // One-time weight transposes (QKV merged)
    wtr3_kernel<<<dim3(1, 12, 72), 256, 0, stream>>>(Wq, Wk, Wv, wqT, wkT, wvT);
    wtr_kernel<<<dim3(12, 12, L_), 256, 0, stream>>>(Wo, woT, D_, D_);
    wtr_kernel<<<dim3(48, 12, L_), 256, 0, stream>>>(W1, w1T, D_, DH_);
    wtr_kernel<<<dim3(12, 48, L_), 256, 0, stream>>>(W2, w2T, DH_, D_);
    if (woutT)
        wtr_kernel<<<dim3(V_ / 64, 12, 1), 256, 0, stream>>>(Wout, woutT, D_, V_);

    for (int l = 0; l < L_; ++l) {
        gemm_qkv64<<<dim3(6, 32, 3), 256, 0, stream>>>(
            hbf, wqT + l * WH, wkT + l * WH, wvT + l * WH,
            bq + l * 768, bk + l * 768, bv + l * 768, qbf, kbf, vtb);

        fattn_kernel<<<dim3(S_ / 64, H_, B_), 256, 0, stream>>>(
            qbf, kbf, vtb, ign, sabbf);

        gemm_wosk<<<dim3(6, 32, 2), 256, 0, stream>>>(
            sabbf, woT + l * WH, bo + l * D_, tmp, tmp1);
        add_ln_kernel<<<M_ / 4, 256, 0, stream>>>(h, tmp, tmp1, z, zbf, 2);

        gemm_bt64<<<dim3(24, 32), 256, 0, stream>>>(
            zbf, w1T + l * WF, b1 + l * DH_, f1bf, DH_, D_, 2);
        gemm_w2sk<<<dim3(6, 32, 2), 256, 0, stream>>>(
            f1bf, w2T + l * WF, b2 + l * D_, tmp, tmp1);
        add_ln_kernel<<<M_ / 4, 256, 0, stream>>>(z, tmp, tmp1, h, hbf, 1);
    }

    if (woutT)
        gemm_deep<<<dim3(V_ / 256, M_ / 256), 512, 0, stream>>>(
            hbf, woutT, bout, outp, V_, D_);
    else
        gemm_f32b<<<dim3(V_ / 128, M_ / 128), 256, 0, stream>>>(
            hbf, Wout, bout, outp, V_, D_);
}

// Round 16
// 440.191 us; speedup vs baseline: 1.0650x; 1.0076x over previous
//
#include <hip/hip_runtime.h>
#include <math.h>

static constexpr int L_ = 2, H_ = 12, D_ = 768, DH_ = 3072, V_ = 32000,
                     S_ = 1024, B_ = 2;
static constexpr int M_ = B_ * S_;  // 2048 token rows

typedef __attribute__((ext_vector_type(4))) float f32x4;
typedef __attribute__((ext_vector_type(8))) short s16x8;   // 8 bf16 = 4 VGPR
typedef __attribute__((ext_vector_type(2))) unsigned int u32x2;
typedef __attribute__((ext_vector_type(4))) unsigned int u32x4;

__device__ __forceinline__ unsigned short f2bf(float f) {
    unsigned u = __builtin_bit_cast(unsigned, f);
    u = (u + 0x7FFFu + ((u >> 16) & 1u)) >> 16;   // RTNE
    return (unsigned short)u;
}
__device__ __forceinline__ unsigned pack2(float a, float b) {
    return (unsigned)f2bf(a) | ((unsigned)f2bf(b) << 16);
}

__device__ __forceinline__ void gld16(const void* g, void* l) {
    __builtin_amdgcn_global_load_lds(
        (const __attribute__((address_space(1))) unsigned int*)g,
        (__attribute__((address_space(3))) unsigned int*)l, 16, 0, 0);
}

// ---------------------------------------------------------------------------
// Weight transpose: in [K][N] fp32 (mat z at z*K*N) -> out [N][K] bf16.
// ---------------------------------------------------------------------------
__global__ __launch_bounds__(256) void wtr_kernel(
    const float* __restrict__ in, unsigned short* __restrict__ out, int K, int N)
{
    __shared__ unsigned short t[64 * 68];
    const size_t mo = (size_t)blockIdx.z * K * N;
    in  += mo; out += mo;
    const int n0 = blockIdx.x * 64, k0 = blockIdx.y * 64;
    const int tid = threadIdx.x;
    const int kr = tid >> 2, nc = (tid & 3) * 16;
    const float* src = in + (size_t)(k0 + kr) * N + n0 + nc;
    #pragma unroll
    for (int j = 0; j < 4; ++j) {
        const float4 v = *(const float4*)(src + j * 4);
        *(u32x2*)&t[kr * 68 + nc + j * 4] = (u32x2){pack2(v.x, v.y), pack2(v.z, v.w)};
    }
    __syncthreads();
    const int nr = tid >> 2, kc = (tid & 3) * 16;
    unsigned short v16[16];
    #pragma unroll
    for (int j = 0; j < 16; ++j) v16[j] = t[(kc + j) * 68 + nr];
    unsigned short* dst = out + (size_t)(n0 + nr) * K + k0 + kc;
    ((u32x4*)dst)[0] = *(u32x4*)&v16[0];
    ((u32x4*)dst)[1] = *(u32x4*)&v16[8];
}

// Merged QKV transpose: 3 matrices x L_*H_ head-slices, one launch.
__global__ __launch_bounds__(256) void wtr3_kernel(
    const float* __restrict__ Wq, const float* __restrict__ Wk,
    const float* __restrict__ Wv, unsigned short* __restrict__ oq,
    unsigned short* __restrict__ ok, unsigned short* __restrict__ ov)
{
    __shared__ unsigned short t[64 * 68];
    const int z = blockIdx.z;
    const int which = z / 24, zz = z - which * 24;
    const float* in = (which == 0) ? Wq : (which == 1) ? Wk : Wv;
    unsigned short* out = (which == 0) ? oq : (which == 1) ? ok : ov;
    const size_t mo = (size_t)zz * D_ * 64;
    in += mo; out += mo;
    const int k0 = blockIdx.y * 64;
    const int tid = threadIdx.x;
    const int kr = tid >> 2, nc = (tid & 3) * 16;
    const float* src = in + (size_t)(k0 + kr) * 64 + nc;
    #pragma unroll
    for (int j = 0; j < 4; ++j) {
        const float4 v = *(const float4*)(src + j * 4);
        *(u32x2*)&t[kr * 68 + nc + j * 4] = (u32x2){pack2(v.x, v.y), pack2(v.z, v.w)};
    }
    __syncthreads();
    const int nr = tid >> 2, kc = (tid & 3) * 16;
    unsigned short v16[16];
    #pragma unroll
    for (int j = 0; j < 16; ++j) v16[j] = t[(kc + j) * 68 + nr];
    unsigned short* dst = out + (size_t)nr * D_ + k0 + kc;
    ((u32x4*)dst)[0] = *(u32x4*)&v16[0];
    ((u32x4*)dst)[1] = *(u32x4*)&v16[8];
}

__device__ __forceinline__ void xcd_decode(int& bx, int& by) {
    const int gx = gridDim.x, gy = gridDim.y;
    const int nwg = gx * gy;
    const int flat = blockIdx.y * gx + blockIdx.x;
    const int s = (flat & 7) * (nwg >> 3) + (flat >> 3);
    bx = s / gy;
    by = s % gy;
}

// ---------------------------------------------------------------------------
// 64x128 tile GEMM — workhorse for mid-size GEMMs. 256 threads = 4 waves 1x4;
// per-wave 64x32, acc 4x2. LDS 24 KiB -> 5+ blocks/CU. Granule-XOR layout.
// act 0: f32+bias. 1: f32+bias+gelu. 2: bf16+bias [M][N].
// 3: V^T bf16+bias [B][H][64][S] (LDS-bounced coalesced). 4: f32 raw (splitK).
// ---------------------------------------------------------------------------
__device__ __forceinline__ void bt64_body(
    const unsigned short* __restrict__ A, const unsigned short* __restrict__ BT,
    const float* __restrict__ bias, void* __restrict__ Cp,
    int N, int K, int act, int k0off, int klen, int bx, int by)
{
    __shared__ unsigned short AB[12288];   // As = AB (8KB), Bs = AB+4096 (16KB)
    unsigned short* As = AB;
    unsigned short* Bs = AB + 4096;
    const int tid = threadIdx.x;
    const int l = tid & 63, w = tid >> 6;
    const int lq = l & 15, lg = l >> 4;
    const int brow = by * 64, bn = bx * 128;

    f32x4 acc[4][2];
    #pragma unroll
    for (int i = 0; i < 4; ++i)
        #pragma unroll
        for (int j = 0; j < 2; ++j) acc[i][j] = (f32x4)0.f;

    const int arow = tid >> 3;                    // 0..31
    const int aq   = (tid & 7) ^ (arow & 7);
    const unsigned short* Abase = A  + (size_t)(brow + arow) * K + k0off + aq * 8;
    const unsigned short* Bbase = BT + (size_t)(bn   + arow) * K + k0off + aq * 8;

    for (int k0 = 0; k0 < klen; k0 += 64) {
        #pragma unroll
        for (int r = 0; r < 2; ++r)
            gld16(Abase + (size_t)r * 32 * K + k0, (char*)As + r * 4096 + tid * 16);
        #pragma unroll
        for (int r = 0; r < 4; ++r)
            gld16(Bbase + (size_t)r * 32 * K + k0, (char*)Bs + r * 4096 + tid * 16);
        __syncthreads();

        #pragma unroll
        for (int kk = 0; kk < 2; ++kk) {
            s16x8 af[4], bf[2];
            #pragma unroll
            for (int mf = 0; mf < 4; ++mf) {
                const int row = mf * 16 + lq;
                const int gg  = (kk * 4 + lg) ^ (row & 7);
                af[mf] = *(const s16x8*)((const char*)As + row * 128 + gg * 16);
            }
            #pragma unroll
            for (int nf = 0; nf < 2; ++nf) {
                const int col = w * 32 + nf * 16 + lq;
                const int gg  = (kk * 4 + lg) ^ (col & 7);
                bf[nf] = *(const s16x8*)((const char*)Bs + col * 128 + gg * 16);
            }
            #pragma unroll
            for (int mf = 0; mf < 4; ++mf)
                #pragma unroll
                for (int nf = 0; nf < 2; ++nf)
                    acc[mf][nf] = __builtin_amdgcn_mfma_f32_16x16x32_bf16(
                        af[mf], bf[nf], acc[mf][nf], 0, 0, 0);
        }
        __syncthreads();
    }

    if (act == 3) {
        #pragma unroll
        for (int nf = 0; nf < 2; ++nf) {
            const int c = w * 32 + nf * 16 + lq;
            const float bb = bias[bn + c];
            #pragma unroll
            for (int mf = 0; mf < 4; ++mf) {
                const int srel = mf * 16 + lg * 4;
                u32x2 pk;
                pk[0] = pack2(acc[mf][nf][0] + bb, acc[mf][nf][1] + bb);
                pk[1] = pack2(acc[mf][nf][2] + bb, acc[mf][nf][3] + bb);
                const int byo = (c * 128 + srel * 2) ^ ((c & 7) << 4);
                *(u32x2*)((char*)AB + byo) = pk;
            }
        }
        __syncthreads();
        const int row = tid >> 1, half = tid & 1;
        const int gcf = bn + row;
        const int head = gcf >> 6, d = gcf & 63;
        const int b = brow >> 10;
        const int sb = (brow & (S_ - 1)) + half * 32;
        unsigned short* dst = (unsigned short*)Cp +
            (((size_t)b * H_ + head) * 64 + d) * S_ + sb;
        #pragma unroll
        for (int u = 0; u < 4; ++u) {
            const int byo = (row * 128 + half * 64 + u * 16) ^ ((row & 7) << 4);
            ((u32x4*)dst)[u] = *(const u32x4*)((const char*)AB + byo);
        }
        return;
    }
    #pragma unroll
    for (int nf = 0; nf < 2; ++nf) {
        const int gcol = bn + w * 32 + nf * 16 + lq;
        const float bb = (act == 4) ? 0.f : bias[gcol];
        #pragma unroll
        for (int mf = 0; mf < 4; ++mf)
            #pragma unroll
            for (int rg = 0; rg < 4; ++rg) {
                const int grow = brow + mf * 16 + lg * 4 + rg;
                float vv = acc[mf][nf][rg] + bb;
                if (act == 1) vv = 0.5f * vv * (1.0f + erff(vv * 0.70710678118654752f));
                if (act == 2)
                    ((unsigned short*)Cp)[(size_t)grow * N + gcol] = f2bf(vv);
                else
                    ((float*)Cp)[(size_t)grow * N + gcol] = vv;
            }
    }
}

__global__ __launch_bounds__(256) void gemm_bt64(
    const unsigned short* __restrict__ A, const unsigned short* __restrict__ BT,
    const float* __restrict__ bias, void* __restrict__ C, int N, int K, int act)
{
    int bx, by; xcd_decode(bx, by);
    bt64_body(A, BT, bias, C, N, K, act, 0, K, bx, by);
}

// QKV, 64-row tiles: grid (6, 32, 3). act2 for q,k; act3 (V^T) for v.
__global__ __launch_bounds__(256) void gemm_qkv64(
    const unsigned short* __restrict__ A,
    const unsigned short* __restrict__ qT, const unsigned short* __restrict__ kT,
    const unsigned short* __restrict__ vT,
    const float* __restrict__ bq, const float* __restrict__ bk, const float* __restrict__ bv,
    unsigned short* __restrict__ q, unsigned short* __restrict__ k,
    unsigned short* __restrict__ v)
{
    const unsigned short* BT; const float* bi; unsigned short* C; int act;
    if (blockIdx.z == 0)      { BT = qT; bi = bq; C = q; act = 2; }
    else if (blockIdx.z == 1) { BT = kT; bi = bk; C = k; act = 2; }
    else                      { BT = vT; bi = bv; C = v; act = 3; }
    int bx, by; xcd_decode(bx, by);
    bt64_body(A, BT, bi, C, 768, 768, act, 0, 768, bx, by);
}

// W2 split-K: grid (6, 32, 2). z=0 -> partial0 (with bias), z=1 -> partial1 raw.
__global__ __launch_bounds__(256) void gemm_w2sk(
    const unsigned short* __restrict__ A, const unsigned short* __restrict__ BT,
    const float* __restrict__ bias, float* __restrict__ C0, float* __restrict__ C1)
{
    int bx, by; xcd_decode(bx, by);
    if (blockIdx.z == 0)
        bt64_body(A, BT, bias, C0, 768, DH_, 0, 0, 1536, bx, by);
    else
        bt64_body(A, BT, bias, C1, 768, DH_, 4, 1536, 1536, bx, by);
}

// Wo split-K: grid (6, 32, 2). K=768 halves.
__global__ __launch_bounds__(256) void gemm_wosk(
    const unsigned short* __restrict__ A, const unsigned short* __restrict__ BT,
    const float* __restrict__ bias, float* __restrict__ C0, float* __restrict__ C1)
{
    int bx, by; xcd_decode(bx, by);
    if (blockIdx.z == 0)
        bt64_body(A, BT, bias, C0, 768, 768, 0, 0, 384, bx, by);
    else
        bt64_body(A, BT, bias, C1, 768, 768, 4, 384, 384, bx, by);
}

// ---------------------------------------------------------------------------
// 256x256 8-wave GEMM for the logits matmul (round-8 schedule, best of 5).
// ---------------------------------------------------------------------------
__global__ __launch_bounds__(512, 2) void gemm_deep(
    const unsigned short* __restrict__ A, const unsigned short* __restrict__ BT,
    const float* __restrict__ bias, float* __restrict__ C, int N, int K)
{
    __shared__ char lds[131072];   // A: c*32768; B: 65536 + c*32768
    const int tid = threadIdx.x;
    const int l = tid & 63, w = tid >> 6;
    const int wr = w >> 2, wc = w & 3;
    const int lq = l & 15, lg = l >> 4;

    int bx, by;
    {
        const int gx = gridDim.x, gy = gridDim.y;
        const int nwg = gx * gy;
        const int flat = blockIdx.y * gx + blockIdx.x;
        const int s = (flat & 7) * (nwg >> 3) + (flat >> 3);
        bx = s / gy; by = s % gy;
    }
    const int brow = by * 256, bn = bx * 256;
    const int NT = K >> 6;   // 12

    const int srow = (w << 3) + (l >> 3);        // 0..63
    const int sgr  = (l & 7) ^ (l >> 3);
    const size_t soff = (size_t)srow * K + sgr * 8;
    const unsigned short* Ag = A  + (size_t)brow * K + soff;
    const unsigned short* Bg = BT + (size_t)bn   * K + soff;
    const size_t r64  = (size_t)64 * K;
    const size_t r128 = (size_t)128 * K;
    char* const dA = lds + w * 1024;
    char* const dB = lds + 65536 + w * 1024;

#define STG_A(CB, HF, KT) do {                                                   \
    gld16(Ag + (size_t)(HF) * r128 + (size_t)(KT) * 64,                          \
          dA + (CB) * 32768 + (HF) * 16384);                                     \
    gld16(Ag + (size_t)(HF) * r128 + r64 + (size_t)(KT) * 64,                    \
          dA + (CB) * 32768 + (HF) * 16384 + 8192); } while (0)
#define STG_B(CB, HF, KT) do {                                                   \
    gld16(Bg + (size_t)(HF) * r128 + (size_t)(KT) * 64,                          \
          dB + (CB) * 32768 + (HF) * 16384);                                     \
    gld16(Bg + (size_t)(HF) * r128 + r64 + (size_t)(KT) * 64,                    \
          dB + (CB) * 32768 + (HF) * 16384 + 8192); } while (0)

    f32x4 acc[8][4];
    #pragma unroll
    for (int i = 0; i < 8; ++i)
        #pragma unroll
        for (int j = 0; j < 4; ++j) acc[i][j] = (f32x4)0.f;

    STG_A(0, 0, 0); STG_A(0, 1, 0); STG_B(0, 0, 0); STG_B(0, 1, 0);
    STG_A(1, 0, 1); STG_B(1, 0, 1);
    asm volatile("s_waitcnt vmcnt(4)" ::: "memory");
    __builtin_amdgcn_s_barrier();

    for (int t = 0; t < NT; ++t) {
        const int c = t & 1;
        const char* Ab = lds + c * 32768;
        const char* Bb = lds + 65536 + c * 32768;
        s16x8 af[4], bf[4];

        #pragma unroll
        for (int mf = 0; mf < 4; ++mf) {
            const int row = wr * 128 + mf * 16 + lq;
            af[mf] = *(const s16x8*)(Ab + row * 128 + ((lg ^ (row & 7)) << 4));
        }
        #pragma unroll
        for (int nf = 0; nf < 4; ++nf) {
            const int col = wc * 64 + nf * 16 + lq;
            bf[nf] = *(const s16x8*)(Bb + col * 128 + ((lg ^ (col & 7)) << 4));
        }
        if (t + 1 < NT) STG_A(c ^ 1, 1, t + 1);
        asm volatile("s_waitcnt lgkmcnt(0)" ::: "memory");
        __builtin_amdgcn_sched_barrier(0);
        __builtin_amdgcn_s_barrier();
        __builtin_amdgcn_s_setprio(1);
        #pragma unroll
        for (int mf = 0; mf < 4; ++mf)
            #pragma unroll
            for (int nf = 0; nf < 4; ++nf)
                acc[mf][nf] = __builtin_amdgcn_mfma_f32_16x16x32_bf16(
                    af[mf], bf[nf], acc[mf][nf], 0, 0, 0);
        __builtin_amdgcn_s_setprio(0);
        __builtin_amdgcn_s_barrier();

        #pragma unroll
        for (int mf = 0; mf < 4; ++mf) {
            const int row = wr * 128 + (mf + 4) * 16 + lq;
            af[mf] = *(const s16x8*)(Ab + row * 128 + ((lg ^ (row & 7)) << 4));
        }
        if (t + 1 < NT) STG_B(c ^ 1, 1, t + 1);
        asm volatile("s_waitcnt lgkmcnt(0)" ::: "memory");
        __builtin_amdgcn_sched_barrier(0);
        __builtin_amdgcn_s_barrier();
        __builtin_amdgcn_s_setprio(1);
        #pragma unroll
        for (int mf = 0; mf < 4; ++mf)
            #pragma unroll
            for (int nf = 0; nf < 4; ++nf)
                acc[mf + 4][nf] = __builtin_amdgcn_mfma_f32_16x16x32_bf16(
                    af[mf], bf[nf], acc[mf + 4][nf], 0, 0, 0);
        __builtin_amdgcn_s_setprio(0);
        __builtin_amdgcn_s_barrier();

        #pragma unroll
        for (int mf = 0; mf < 4; ++mf) {
            const int row = wr * 128 + mf * 16 + lq;
            af[mf] = *(const s16x8*)(Ab + row * 128 + (((4 + lg) ^ (row & 7)) << 4));
        }
        #pragma unroll
        for (int nf = 0; nf < 4; ++nf) {
            const int col = wc * 64 + nf * 16 + lq;
            bf[nf] = *(const s16x8*)(Bb + col * 128 + (((4 + lg) ^ (col & 7)) << 4));
        }
        asm volatile("s_waitcnt lgkmcnt(0)" ::: "memory");
        __builtin_amdgcn_sched_barrier(0);
        __builtin_amdgcn_s_barrier();
        __builtin_amdgcn_s_setprio(1);
        #pragma unroll
        for (int mf = 0; mf < 4; ++mf)
            #pragma unroll
            for (int nf = 0; nf < 4; ++nf)
                acc[mf][nf] = __builtin_amdgcn_mfma_f32_16x16x32_bf16(
                    af[mf], bf[nf], acc[mf][nf], 0, 0, 0);
        __builtin_amdgcn_s_setprio(0);
        __builtin_amdgcn_s_barrier();

        #pragma unroll
        for (int mf = 0; mf < 4; ++mf) {
            const int row = wr * 128 + (mf + 4) * 16 + lq;
            af[mf] = *(const s16x8*)(Ab + row * 128 + (((4 + lg) ^ (row & 7)) << 4));
        }
        asm volatile("s_waitcnt lgkmcnt(0)" ::: "memory");
        __builtin_amdgcn_sched_barrier(0);
        __builtin_amdgcn_s_barrier();
        __builtin_amdgcn_s_setprio(1);
        #pragma unroll
        for (int mf = 0; mf < 4; ++mf)
            #pragma unroll
            for (int nf = 0; nf < 4; ++nf)
                acc[mf + 4][nf] = __builtin_amdgcn_mfma_f32_16x16x32_bf16(
                    af[mf], bf[nf], acc[mf + 4][nf], 0, 0, 0);
        __builtin_amdgcn_s_setprio(0);

        if (t + 2 < NT) {
            STG_A(c, 0, t + 2); STG_B(c, 0, t + 2);
            asm volatile("s_waitcnt vmcnt(4)" ::: "memory");
            __builtin_amdgcn_s_barrier();
        } else if (t + 1 < NT) {
            asm volatile("s_waitcnt vmcnt(0)" ::: "memory");
            __builtin_amdgcn_s_barrier();
        }
    }
#undef STG_A
#undef STG_B

    #pragma unroll
    for (int nf = 0; nf < 4; ++nf) {
        const int gcol = bn + wc * 64 + nf * 16 + lq;
        const float bb = bias[gcol];
        #pragma unroll
        for (int mf = 0; mf < 8; ++mf)
            #pragma unroll
            for (int rg = 0; rg < 4; ++rg) {
                const int grow = brow + wr * 128 + mf * 16 + lg * 4 + rg;
                C[(size_t)grow * N + gcol] = acc[mf][nf][rg] + bb;
            }
    }
}

// ---------------------------------------------------------------------------
// Fallback GEMM (fp32 B in [K][N]) — only if ws can't hold transposed Wout.
// ---------------------------------------------------------------------------
__global__ __launch_bounds__(256) void gemm_f32b(
    const unsigned short* __restrict__ A, const float* __restrict__ B,
    const float* __restrict__ bias, float* __restrict__ C, int N, int K)
{
    __shared__ unsigned short As[8192];
    __shared__ unsigned short Bs[8192];
    const int tid = threadIdx.x;
    const int l   = tid & 63, wid = tid >> 6;
    const int wr  = wid >> 1, wc = wid & 1;
    const int brow = blockIdx.y * 128, bn = blockIdx.x * 128;
    f32x4 acc[4][4];
    #pragma unroll
    for (int i = 0; i < 4; ++i)
        #pragma unroll
        for (int j = 0; j < 4; ++j) acc[i][j] = (f32x4)0.f;
    const int arow = tid >> 3;
    const int aq   = (tid & 7) ^ (arow & 7);
    const int bkq  = tid >> 5, bnq = tid & 31;
    for (int k0 = 0; k0 < K; k0 += 64) {
        #pragma unroll
        for (int r = 0; r < 4; ++r)
            gld16(A + (size_t)(brow + r * 32 + arow) * K + k0 + aq * 8,
                  (char*)As + r * 4096 + wid * 1024);
        #pragma unroll
        for (int r = 0; r < 2; ++r) {
            const int kb = r * 32 + bkq * 4;
            const float* pp = B + (size_t)(k0 + kb) * N + bn + bnq * 4;
            const float4 v0 = *(const float4*)(pp);
            const float4 v1 = *(const float4*)(pp + N);
            const float4 v2 = *(const float4*)(pp + 2 * (size_t)N);
            const float4 v3 = *(const float4*)(pp + 3 * (size_t)N);
            const int g = kb >> 3, bytek = (kb & 4) * 2;
            const float* f0 = (const float*)&v0; const float* f1 = (const float*)&v1;
            const float* f2 = (const float*)&v2; const float* f3 = (const float*)&v3;
            #pragma unroll
            for (int i = 0; i < 4; ++i) {
                const int n = bnq * 4 + i;
                char* dst = (char*)Bs + n * 128 + ((g ^ (n & 7)) * 16) + bytek;
                *(u32x2*)dst = (u32x2){pack2(f0[i], f1[i]), pack2(f2[i], f3[i])};
            }
        }
        __syncthreads();
        #pragma unroll
        for (int kk = 0; kk < 2; ++kk) {
            s16x8 af[4], bf[4];
            #pragma unroll
            for (int mf = 0; mf < 4; ++mf) {
                const int row = wr * 64 + mf * 16 + (l & 15);
                const int gg  = (kk * 4 + (l >> 4)) ^ (row & 7);
                af[mf] = *(const s16x8*)((const char*)As + row * 128 + gg * 16);
            }
            #pragma unroll
            for (int nf = 0; nf < 4; ++nf) {
                const int col = wc * 64 + nf * 16 + (l & 15);
                const int gg  = (kk * 4 + (l >> 4)) ^ (col & 7);
                bf[nf] = *(const s16x8*)((const char*)Bs + col * 128 + gg * 16);
            }
            #pragma unroll
            for (int mf = 0; mf < 4; ++mf)
                #pragma unroll
                for (int nf = 0; nf < 4; ++nf)
                    acc[mf][nf] = __builtin_amdgcn_mfma_f32_16x16x32_bf16(
                        af[mf], bf[nf], acc[mf][nf], 0, 0, 0);
        }
        __syncthreads();
    }
    const int lr = l >> 4, lc = l & 15;
    #pragma unroll
    for (int nf = 0; nf < 4; ++nf) {
        const int gcol = bn + wc * 64 + nf * 16 + lc;
        const float bb = bias[gcol];
        #pragma unroll
        for (int mf = 0; mf < 4; ++mf)
            #pragma unroll
            for (int rg = 0; rg < 4; ++rg) {
                const int grow = brow + wr * 64 + mf * 16 + lr * 4 + rg;
                C[(size_t)grow * N + gcol] = acc[mf][nf][rg] + bb;
            }
    }
}

// ---------------------------------------------------------------------------
// Flash attention v4: paired KV tiles — both buffers = two halves of a
// 128-key step. One stage+barrier, one online-softmax (one max/sum reduce,
// one rescale) per 128 keys. Mask addend + setprio + balance remap kept.
// ---------------------------------------------------------------------------
__global__ __launch_bounds__(256) void fattn_kernel(
    const unsigned short* __restrict__ qm, const unsigned short* __restrict__ km,
    const unsigned short* __restrict__ vt, const int* __restrict__ ign,
    unsigned short* __restrict__ sab)
{
    __shared__ unsigned short Ks[2][4096];
    __shared__ unsigned short VTs[2][4096];
    __shared__ float addvs[2][64];
    __shared__ unsigned short PTs[4][1024];

    const int hh = blockIdx.y, b = blockIdx.z;
    const int zy = b * 12 + hh;
    const int qt = (zy >= 16) ? (15 - blockIdx.x) : blockIdx.x;

    const int tid = threadIdx.x;
    const int l = tid & 63, w = tid >> 6;
    const int g = l >> 4, lq = l & 15;
    const int i = qt * 64 + w * 16 + lq;

    const size_t qgb = ((size_t)(b * S_ + i)) * D_ + hh * 64;
    const s16x8 qf0 = *(const s16x8*)(qm + qgb + g * 8);
    const s16x8 qf1 = *(const s16x8*)(qm + qgb + 32 + g * 8);

    f32x4 accO[4];
    #pragma unroll
    for (int d = 0; d < 4; ++d) accO[d] = (f32x4)0.f;
    float mrun = -1e30f, lrun = 0.f;

    const int srow = tid >> 3, sg = tid & 7;
    const size_t kbase = (size_t)(b * S_) * D_ + hh * 64;
    const size_t vbase = ((size_t)(b * H_ + hh) * 64) * S_;

    auto stage = [&](int t, int bufi) {
        const int j0 = t * 64;
        #pragma unroll
        for (int r = 0; r < 2; ++r) {
            const int row = r * 32 + srow;
            const int gsw = (sg ^ (row & 7)) * 8;
            gld16(km + kbase + (size_t)(j0 + row) * D_ + gsw,
                  (char*)&Ks[bufi][0] + (r * 256 + tid) * 16);
            gld16(vt + vbase + (size_t)row * S_ + j0 + gsw,
                  (char*)&VTs[bufi][0] + (r * 256 + tid) * 16);
        }
        if (tid < 64)
            addvs[bufi][tid] = (ign[b * S_ + j0 + tid] == 0) ? 0.f : -INFINITY;
    };

    // one QK sub-step: S^T for 64 keys from buffer bufi
    auto qk_sub = [&](int bufi, f32x4* sacc) {
        #pragma unroll
        for (int kf = 0; kf < 4; ++kf) sacc[kf] = (f32x4)0.f;
        #pragma unroll
        for (int kk = 0; kk < 2; ++kk) {
            const s16x8 qv = kk ? qf1 : qf0;
            #pragma unroll
            for (int kf = 0; kf < 4; ++kf) {
                const int row = kf * 16 + lq;
                const s16x8 kv = *(const s16x8*)((const char*)&Ks[bufi][0] + row * 128 +
                                                 (((kk * 4 + g) ^ (row & 7)) * 16));
                sacc[kf] = __builtin_amdgcn_mfma_f32_16x16x32_bf16(kv, qv, sacc[kf], 0, 0, 0);
            }
        }
    };

    // mask for sub-tile t (j0 = t*64) into sacc; updates tmax
    auto mask_sub = [&](int t, int bufi, f32x4* sacc, float& tmax) {
        const int j0 = t * 64;
        f32x4 adv[4];
        #pragma unroll
        for (int kf = 0; kf < 4; ++kf)
            adv[kf] = *(const f32x4*)&addvs[bufi][kf * 16 + g * 4];
        if (t < qt) {
            #pragma unroll
            for (int kf = 0; kf < 4; ++kf)
                #pragma unroll
                for (int rg = 0; rg < 4; ++rg) {
                    const float s = fmaf(sacc[kf][rg], 0.125f, adv[kf][rg]);
                    sacc[kf][rg] = s;
                    tmax = fmaxf(tmax, s);
                }
        } else {
            #pragma unroll
            for (int kf = 0; kf < 4; ++kf)
                #pragma unroll
                for (int rg = 0; rg < 4; ++rg) {
                    const int j = j0 + kf * 16 + g * 4 + rg;
                    const float sv = sacc[kf][rg] * 0.125f;
                    const float s = (j > i) ? -INFINITY
                                  : (j == i ? sv : sv + adv[kf][rg]);
                    sacc[kf][rg] = s;
                    tmax = fmaxf(tmax, s);
                }
        }
    };

    // PV for one 64-key sub-tile: P (bf16, via per-wave LDS) @ V^T[bufi]
    auto pv_sub = [&](int bufi, const f32x4* sacc) {
        char* ptw = (char*)&PTs[w][0];
        #pragma unroll
        for (int kf = 0; kf < 4; ++kf) {
            u32x2 pk;
            pk[0] = pack2(sacc[kf][0], sacc[kf][1]);
            pk[1] = pack2(sacc[kf][2], sacc[kf][3]);
            *(u32x2*)(ptw + lq * 128 +
                      (((kf * 2 + (g >> 1)) ^ (lq & 7)) * 16) + (g & 1) * 8) = pk;
        }
        __builtin_amdgcn_s_setprio(1);
        #pragma unroll
        for (int kh = 0; kh < 2; ++kh) {
            const s16x8 pb = *(const s16x8*)(ptw + lq * 128 +
                                             (((kh * 4 + g) ^ (lq & 7)) * 16));
            #pragma unroll
            for (int df = 0; df < 4; ++df) {
                const int row = df * 16 + lq;
                const s16x8 vf = *(const s16x8*)((const char*)&VTs[bufi][0] + row * 128 +
                                                 (((kh * 4 + g) ^ (row & 7)) * 16));
                accO[df] = __builtin_amdgcn_mfma_f32_16x16x32_bf16(vf, pb, accO[df], 0, 0, 0);
            }
        }
        __builtin_amdgcn_s_setprio(0);
    };

    for (int tt = 0; tt <= qt; tt += 2) {
        const bool have2 = (tt + 1 <= qt);
        stage(tt, 0);
        if (have2) stage(tt + 1, 1);
        asm volatile("s_waitcnt vmcnt(0) lgkmcnt(0)" ::: "memory");
        __syncthreads();

        f32x4 sacc0[4], sacc1[4];
        __builtin_amdgcn_s_setprio(1);
        qk_sub(0, sacc0);
        if (have2) qk_sub(1, sacc1);
        __builtin_amdgcn_s_setprio(0);

        float tmax = -INFINITY;
        mask_sub(tt, 0, sacc0, tmax);
        if (have2) mask_sub(tt + 1, 1, sacc1, tmax);

        tmax = fmaxf(tmax, __shfl_xor(tmax, 16));
        tmax = fmaxf(tmax, __shfl_xor(tmax, 32));
        const float mnew = fmaxf(mrun, tmax);
        const float fac = __expf(mrun - mnew);
        float psum = 0.f;
        #pragma unroll
        for (int kf = 0; kf < 4; ++kf)
            #pragma unroll
            for (int rg = 0; rg < 4; ++rg) {
                const float p = __expf(sacc0[kf][rg] - mnew);
                sacc0[kf][rg] = p;
                psum += p;
            }
        if (have2) {
            #pragma unroll
            for (int kf = 0; kf < 4; ++kf)
                #pragma unroll
                for (int rg = 0; rg < 4; ++rg) {
                    const float p = __expf(sacc1[kf][rg] - mnew);
                    sacc1[kf][rg] = p;
                    psum += p;
                }
        }
        psum += __shfl_xor(psum, 16);
        psum += __shfl_xor(psum, 32);
        lrun = lrun * fac + psum;
        mrun = mnew;
        #pragma unroll
        for (int d = 0; d < 4; ++d) accO[d] *= fac;

        pv_sub(0, sacc0);
        if (have2) pv_sub(1, sacc1);
        __syncthreads();   // before next pair overwrites both buffers
    }

    const float inv = 1.0f / lrun;
    unsigned short* orow = sab + ((size_t)(b * S_ + i)) * D_ + hh * 64;
    #pragma unroll
    for (int df = 0; df < 4; ++df) {
        u32x2 pk;
        pk[0] = pack2(accO[df][0] * inv, accO[df][1] * inv);
        pk[1] = pack2(accO[df][2] * inv, accO[df][3] * inv);
        *(u32x2*)(orow + df * 16 + g * 4) = pk;
    }
}

// ---------------------------------------------------------------------------
__global__ __launch_bounds__(256) void embed_kernel(
    const int* __restrict__ x, const int* __restrict__ ign,
    const float* __restrict__ emb, const float* __restrict__ pos,
    float* __restrict__ h, unsigned short* __restrict__ hbf)
{
    const int row = blockIdx.x;
    const int s = row & (S_ - 1);
    const int tok = x[row];
    const float keep = (ign[row] == 0) ? 1.0f : 0.0f;
    const float* er = emb + (size_t)tok * D_;
    const float* pr = pos + (size_t)s * D_;
    float* hr = h + (size_t)row * D_;
    unsigned short* hb = hbf + (size_t)row * D_;
    for (int d = threadIdx.x; d < D_; d += 256) {
        const float t = er[d] + pr[d] * keep;
        hr[d] = t;
        hb[d] = f2bf(t);
    }
}

// ---------------------------------------------------------------------------
// out = LN(X + Y0)            (mode 0)
// out = LN(X + gelu(Y0 + Y1)) (mode 1, W2 split-K partials; bias in Y0)
// out = LN(X + Y0 + Y1)       (mode 2, Wo split-K partials; bias in Y0)
// ---------------------------------------------------------------------------
__global__ __launch_bounds__(256) void add_ln_kernel(
    const float* __restrict__ X, const float* __restrict__ Y0,
    const float* __restrict__ Y1, float* __restrict__ out,
    unsigned short* __restrict__ outbf, int mode)
{
    const int row = blockIdx.x * 4 + (threadIdx.x >> 6);
    const int l = threadIdx.x & 63;
    const float4* xr = (const float4*)(X + (size_t)row * D_);
    const float4* y0 = (const float4*)(Y0 + (size_t)row * D_);
    const float4* y1 = (const float4*)(Y1 + (size_t)row * D_);
    float4 t[3];
    float s0 = 0.f;
    #pragma unroll
    for (int k = 0; k < 3; ++k) {
        const float4 a = xr[k * 64 + l];
        float4 b = y0[k * 64 + l];
        if (mode != 0) {
            const float4 c = y1[k * 64 + l];
            b.x += c.x; b.y += c.y; b.z += c.z; b.w += c.w;
        }
        if (mode == 1) {
            b.x = 0.5f * b.x * (1.0f + erff(b.x * 0.70710678118654752f));
            b.y = 0.5f * b.y * (1.0f + erff(b.y * 0.70710678118654752f));
            b.z = 0.5f * b.z * (1.0f + erff(b.z * 0.70710678118654752f));
            b.w = 0.5f * b.w * (1.0f + erff(b.w * 0.70710678118654752f));
        }
        t[k].x = a.x + b.x; t[k].y = a.y + b.y;
        t[k].z = a.z + b.z; t[k].w = a.w + b.w;
        s0 += t[k].x + t[k].y + t[k].z + t[k].w;
    }
    #pragma unroll
    for (int o = 32; o; o >>= 1) s0 += __shfl_xor(s0, o);
    const float mu = s0 * (1.0f / D_);
    float s1 = 0.f;
    #pragma unroll
    for (int k = 0; k < 3; ++k) {
        t[k].x -= mu; t[k].y -= mu; t[k].z -= mu; t[k].w -= mu;
        s1 += t[k].x * t[k].x + t[k].y * t[k].y + t[k].z * t[k].z + t[k].w * t[k].w;
    }
    #pragma unroll
    for (int o = 32; o; o >>= 1) s1 += __shfl_xor(s1, o);
    const float inv = 1.0f / sqrtf(s1 * (1.0f / D_));
    float4* orow = (float4*)(out + (size_t)row * D_);
    u32x2* obf = (u32x2*)(outbf + (size_t)row * D_);
    #pragma unroll
    for (int k = 0; k < 3; ++k) {
        float4 r;
        r.x = t[k].x * inv; r.y = t[k].y * inv;
        r.z = t[k].z * inv; r.w = t[k].w * inv;
        orow[k * 64 + l] = r;
        u32x2 pk; pk[0] = pack2(r.x, r.y); pk[1] = pack2(r.z, r.w);
        obf[k * 64 + l] = pk;
    }
}

// ---------------------------------------------------------------------------
extern "C" void kernel_launch(void* const* d_in, const int* in_sizes, int n_in,
                              void* d_out, int out_size, void* d_ws, size_t ws_size,
                              hipStream_t stream)
{
    const int*   x    = (const int*)d_in[0];
    const int*   ign  = (const int*)d_in[1];
    const float* emb  = (const float*)d_in[2];
    const float* pos  = (const float*)d_in[3];
    const float* Wq   = (const float*)d_in[4];
    const float* bq   = (const float*)d_in[5];
    const float* Wk   = (const float*)d_in[6];
    const float* bk   = (const float*)d_in[7];
    const float* Wv   = (const float*)d_in[8];
    const float* bv   = (const float*)d_in[9];
    const float* Wo   = (const float*)d_in[10];
    const float* bo   = (const float*)d_in[11];
    const float* W1   = (const float*)d_in[12];
    const float* b1   = (const float*)d_in[13];
    const float* W2   = (const float*)d_in[14];
    const float* b2   = (const float*)d_in[15];
    const float* Wout = (const float*)d_in[16];
    const float* bout = (const float*)d_in[17];
    float* outp = (float*)d_out;

    const size_t RC = (size_t)M_ * D_;        // 1572864
    const size_t F1 = (size_t)M_ * DH_;       // 6291456
    const size_t WH = (size_t)H_ * 64 * D_;   // 589824
    const size_t WF = (size_t)D_ * DH_;       // 2359296
    const size_t WOUTE = (size_t)V_ * D_;     // 24576000

    char* wsp = (char*)d_ws;
    size_t wsleft = ws_size;
    char* dop = (char*)d_out;
    auto alloc = [&](size_t bytes, bool must_ws) -> void* {
        bytes = (bytes + 255) & ~(size_t)255;
        if (wsleft >= bytes) { void* p = wsp; wsp += bytes; wsleft -= bytes; return p; }
        if (must_ws) return nullptr;
        void* p = dop; dop += bytes; return p;
    };

    unsigned short* hbf   = (unsigned short*)alloc(RC * 2, true);
    unsigned short* woutT = (unsigned short*)alloc(WOUTE * 2, true);
    float* h    = (float*)alloc(RC * 4, false);
    float* z    = (float*)alloc(RC * 4, false);
    float* tmp  = (float*)alloc(RC * 4, false);
    float* tmp1 = (float*)alloc(RC * 4, false);
    unsigned short* zbf   = (unsigned short*)alloc(RC * 2, false);
    unsigned short* sabbf = (unsigned short*)alloc(RC * 2, false);
    unsigned short* qbf   = (unsigned short*)alloc(RC * 2, false);
    unsigned short* kbf   = (unsigned short*)alloc(RC * 2, false);
    unsigned short* vtb   = (unsigned short*)alloc(RC * 2, false);
    unsigned short* f1bf  = (unsigned short*)alloc(F1 * 2, false);
    unsigned short* wqT = (unsigned short*)alloc(L_ * WH * 2, false);
    unsigned short* wkT = (unsigned short*)alloc(L_ * WH * 2, false);
    unsigned short* wvT = (unsigned short*)alloc(L_ * WH * 2, false);
    unsigned short* woT = (unsigned short*)alloc(L_ * WH * 2, false);
    unsigned short* w1T = (unsigned short*)alloc(L_ * WF * 2, false);
    unsigned short* w2T = (unsigned short*)alloc(L_ * WF * 2, false);

    embed_kernel<<<M_, 256, 0, stream>>>(x, ign, emb, pos, h, hbf);

    // One-time weight transposes (QKV merged)
    wtr3_kernel<<<dim3(1, 12, 72), 256, 0, stream>>>(Wq, Wk, Wv, wqT, wkT, wvT);
    wtr_kernel<<<dim3(12, 12, L_), 256, 0, stream>>>(Wo, woT, D_, D_);
    wtr_kernel<<<dim3(48, 12, L_), 256, 0, stream>>>(W1, w1T, D_, DH_);
    wtr_kernel<<<dim3(12, 48, L_), 256, 0, stream>>>(W2, w2T, DH_, D_);
    if (woutT)
        wtr_kernel<<<dim3(V_ / 64, 12, 1), 256, 0, stream>>>(Wout, woutT, D_, V_);

    for (int l = 0; l < L_; ++l) {
        gemm_qkv64<<<dim3(6, 32, 3), 256, 0, stream>>>(
            hbf, wqT + l * WH, wkT + l * WH, wvT + l * WH,
            bq + l * 768, bk + l * 768, bv + l * 768, qbf, kbf, vtb);

        fattn_kernel<<<dim3(S_ / 64, H_, B_), 256, 0, stream>>>(
            qbf, kbf, vtb, ign, sabbf);

        gemm_wosk<<<dim3(6, 32, 2), 256, 0, stream>>>(
            sabbf, woT + l * WH, bo + l * D_, tmp, tmp1);
        add_ln_kernel<<<M_ / 4, 256, 0, stream>>>(h, tmp, tmp1, z, zbf, 2);

        gemm_bt64<<<dim3(24, 32), 256, 0, stream>>>(
            zbf, w1T + l * WF, b1 + l * DH_, f1bf, DH_, D_, 2);
        gemm_w2sk<<<dim3(6, 32, 2), 256, 0, stream>>>(
            f1bf, w2T + l * WF, b2 + l * D_, tmp, tmp1);
        add_ln_kernel<<<M_ / 4, 256, 0, stream>>>(z, tmp, tmp1, h, hbf, 1);
    }

    if (woutT)
        gemm_deep<<<dim3(V_ / 256, M_ / 256), 512, 0, stream>>>(
            hbf, woutT, bout, outp, V_, D_);
    else
        gemm_f32b<<<dim3(V_ / 128, M_ / 128), 256, 0, stream>>>(
            hbf, Wout, bout, outp, V_, D_);
}